// Round 3
// baseline (355.175 us; speedup 1.0000x reference)
//
#include <hip/hip_runtime.h>
#include <hip/hip_cooperative_groups.h>
#include <math.h>

namespace cg = cooperative_groups;
#define TPB 256

typedef float vf4 __attribute__((ext_vector_type(4)));

__device__ __forceinline__ float gelu_f(float x) {
    return 0.5f * x * (1.0f + erff(x * 0.70710678118654752f));
}
__device__ __forceinline__ float gate_f(float x) {
    float si = x / (1.0f + expf(-x));
    return 1.0f + tanhf(si);
}

struct CoopArgs {
    const float *ec, *ea, *fln_g, *fln_b;
    const float *tok_effect;
    const float *fuse_w1, *fuse_b1, *fuse_w2, *fuse_b2;
    const float *delta_ln_g, *delta_ln_b, *eff_ln_g, *eff_ln_b;
    const float *delta_w, *delta_b, *eff_w1, *eff_b1, *eff_w2, *eff_b2;
    const float *qg_w, *qg_b, *kg_w, *kg_b, *u_w, *v_w;
    float *cat_ln, *ctx, *dln, *eln, *pp, *wu;
    float *part1, *part2, *partA, *partB;
    float *out_de, *out_es, *out_qg, *out_kg, *out_ep;
};

// 64x64 output tile, one K-slice of a split-K GEMM. X supplied by a loader
// functor (enables lazy epilogue-fusion of the previous GEMM's partials).
template <class XL>
__device__ __forceinline__ void gemm_tile(XL xload, const float* __restrict__ W, int Wld, int cb,
                                          int k0, int kslice, float* part, int totN, int gcol, int s,
                                          float* xs, float* wt)
{
    const int t = threadIdx.x;
    const int tr4 = (t >> 4) << 2;
    const int tc4 = (t & 15) << 2;
    float acc[4][4] = {{0.f,0.f,0.f,0.f},{0.f,0.f,0.f,0.f},{0.f,0.f,0.f,0.f},{0.f,0.f,0.f,0.f}};
    for (int kc = 0; kc < kslice; kc += 32) {
        for (int n = t; n < 2048; n += TPB) {
            int r = n >> 5, k = n & 31;
            xs[(k << 6) + r] = xload(r, k0 + kc + k);
        }
        for (int n = t; n < 2048; n += TPB) {
            int k = n >> 6, c = n & 63;
            wt[k * 68 + c] = W[(size_t)(k0 + kc + k) * Wld + cb + c];
        }
        __syncthreads();
#pragma unroll
        for (int k = 0; k < 32; ++k) {
            float4 xv = *(const float4*)&xs[(k << 6) + tr4];
            float4 wv = *(const float4*)&wt[k * 68 + tc4];
            acc[0][0] += xv.x * wv.x; acc[0][1] += xv.x * wv.y; acc[0][2] += xv.x * wv.z; acc[0][3] += xv.x * wv.w;
            acc[1][0] += xv.y * wv.x; acc[1][1] += xv.y * wv.y; acc[1][2] += xv.y * wv.z; acc[1][3] += xv.y * wv.w;
            acc[2][0] += xv.z * wv.x; acc[2][1] += xv.z * wv.y; acc[2][2] += xv.z * wv.z; acc[2][3] += xv.z * wv.w;
            acc[3][0] += xv.w * wv.x; acc[3][1] += xv.w * wv.y; acc[3][2] += xv.w * wv.z; acc[3][3] += xv.w * wv.w;
        }
        __syncthreads();
    }
    float* pp = part + (size_t)(s * 64 + tr4) * totN + gcol + tc4;
#pragma unroll
    for (int i = 0; i < 4; ++i)
#pragma unroll
        for (int j = 0; j < 4; ++j)
            pp[i * totN + j] = acc[i][j];
}

__global__ __launch_bounds__(TPB, 1) void k_coop(CoopArgs A)
{
    __shared__ float smem[8448];   // 33.8 KB: gemm xs(2048)+wt(2176), or wu us[64][132]
    __shared__ float red[4];
    float* xs = smem;
    float* wt = smem + 2048;
    cg::grid_group grid = cg::this_grid();
    const int blk = blockIdx.x, t = threadIdx.x;

    // ================= S0: concat-LN (blocks 0..63) + pool1 (all, 3 tasks) =================
    if (blk < 64) {
        int r = blk;
        float v[6]; float sum = 0.f;
#pragma unroll
        for (int j = 0; j < 6; ++j) {
            int c = t + j * TPB;
            float x = (c < 768) ? A.ec[r * 768 + c] : A.ea[r * 768 + (c - 768)];
            v[j] = x; sum += x;
        }
#pragma unroll
        for (int o_ = 32; o_ > 0; o_ >>= 1) sum += __shfl_xor(sum, o_);
        if ((t & 63) == 0) red[t >> 6] = sum;
        __syncthreads();
        sum = red[0] + red[1] + red[2] + red[3];
        float mean = sum * (1.f / 1536.f);
        __syncthreads();
        float s2 = 0.f;
#pragma unroll
        for (int j = 0; j < 6; ++j) { float d = v[j] - mean; s2 += d * d; }
#pragma unroll
        for (int o_ = 32; o_ > 0; o_ >>= 1) s2 += __shfl_xor(s2, o_);
        if ((t & 63) == 0) red[t >> 6] = s2;
        __syncthreads();
        s2 = red[0] + red[1] + red[2] + red[3];
        float rstd = rsqrtf(s2 * (1.f / 1536.f) + 1e-5f);
#pragma unroll
        for (int j = 0; j < 6; ++j) {
            int c = t + j * TPB;
            A.cat_ln[r * 1536 + c] = (v[j] - mean) * rstd * A.fln_g[c] + A.fln_b[c];
        }
    }
#pragma unroll
    for (int i = 0; i < 3; ++i) {
        int m = blk * 3 + i;               // 0..767
        int cch = m % 3, b = (m / 3) % 64, qz = m / 192;
        int c = cch * TPB + t;
        const float* base = A.tok_effect + (size_t)(b * 256 + qz * 64) * 768 + c;
        float s = 0.f;
#pragma unroll 16
        for (int q = 0; q < 64; ++q) s += base[(size_t)q * 768];
        A.pp[(qz * 64 + b) * 768 + c] = s;
    }
    grid.sync();

    // ================= S1: fuse1 partials (12 ct x 12 s, kslice=128) =================
    if (blk < 144) {
        int ct = blk % 12, s = blk / 12;
        const float* cl = A.cat_ln;
        auto xl = [&](int r, int k) { return cl[r * 1536 + k]; };
        gemm_tile(xl, A.fuse_w1, 768, ct * 64, s * 128, 128, A.part1, 768, ct * 64, s, xs, wt);
    }
    grid.sync();

    // ================= S2: fuse2 partials, X = gelu(sum part1 + b1) lazily =================
    if (blk < 144) {
        int ct = blk % 12, s = blk / 12;
        const float* p1 = A.part1; const float* b1 = A.fuse_b1;
        auto xl = [&](int r, int k) {
            float v = b1[k];
#pragma unroll
            for (int q = 0; q < 12; ++q) v += p1[(size_t)(q * 64 + r) * 768 + k];
            return gelu_f(v);
        };
        gemm_tile(xl, A.fuse_w2, 768, ct * 64, s * 64, 64, A.part2, 768, ct * 64, s, xs, wt);
    }
    grid.sync();

    // ================= S3: fuse2 epilogue + dual LN -> ctx, dln, eln =================
    if (blk < 64) {
        int r = blk;
        float v[3]; float sum = 0.f;
#pragma unroll
        for (int j = 0; j < 3; ++j) {
            int c = t + j * TPB;
            float x = A.fuse_b2[c];
#pragma unroll
            for (int s = 0; s < 12; ++s) x += A.part2[(size_t)(s * 64 + r) * 768 + c];
            v[j] = x; sum += x;
            A.ctx[r * 768 + c] = x;
        }
#pragma unroll
        for (int o_ = 32; o_ > 0; o_ >>= 1) sum += __shfl_xor(sum, o_);
        if ((t & 63) == 0) red[t >> 6] = sum;
        __syncthreads();
        sum = red[0] + red[1] + red[2] + red[3];
        float mean = sum * (1.f / 768.f);
        __syncthreads();
        float s2 = 0.f;
#pragma unroll
        for (int j = 0; j < 3; ++j) { float d = v[j] - mean; s2 += d * d; }
#pragma unroll
        for (int o_ = 32; o_ > 0; o_ >>= 1) s2 += __shfl_xor(s2, o_);
        if ((t & 63) == 0) red[t >> 6] = s2;
        __syncthreads();
        s2 = red[0] + red[1] + red[2] + red[3];
        float rstd = rsqrtf(s2 * (1.f / 768.f) + 1e-5f);
#pragma unroll
        for (int j = 0; j < 3; ++j) {
            int c = t + j * TPB;
            float xh = (v[j] - mean) * rstd;
            A.dln[r * 768 + c] = xh * A.delta_ln_g[c] + A.delta_ln_b[c];
            A.eln[r * 768 + c] = xh * A.eff_ln_g[c] + A.eff_ln_b[c];
        }
    }
    grid.sync();

    // ================= S4: batchA partials: delta|eff1|qg|kg (56 ct x 4 s, kslice=192) =================
    if (blk < 224) {
        int ct = blk % 56, s = blk / 56;
        const float* X; const float* W; int Wld, cb;
        if (ct < 12)      { X = A.dln; W = A.delta_w; Wld = 768;  cb = ct * 64; }
        else if (ct < 24) { X = A.eln; W = A.eff_w1;  Wld = 768;  cb = (ct - 12) * 64; }
        else if (ct < 40) { X = A.ctx; W = A.qg_w;    Wld = 1024; cb = (ct - 24) * 64; }
        else              { X = A.ctx; W = A.kg_w;    Wld = 1024; cb = (ct - 40) * 64; }
        auto xl = [&](int r, int k) { return X[r * 768 + k]; };
        gemm_tile(xl, W, Wld, cb, s * 192, 192, A.partA, 3584, ct * 64, s, xs, wt);
    }
    grid.sync();

    // ================= S5: batchA epilogue/outputs (blocks 0..31) ||
    //                      batchB partials with lazy X (blocks 32..255; 28 ct x 8 s, kslice=96) =================
    if (blk < 32) {
#pragma unroll
        for (int ii = 0; ii < 28; ++ii) {
            int idx = blk * TPB + t + ii * 8192;    // 64*3584 = 229376 = 28*8192
            int r = idx / 3584, c = idx - r * 3584;
            if (c >= 768 && c < 1536) continue;     // eff1 consumed lazily, no output
            float v = A.partA[(size_t)r * 3584 + c] + A.partA[(size_t)(64 + r) * 3584 + c]
                    + A.partA[(size_t)(128 + r) * 3584 + c] + A.partA[(size_t)(192 + r) * 3584 + c];
            if (c < 768) {
                float de = v + A.delta_b[c];
                A.out_de[r * 768 + c] = de;
                float s4 = A.pp[r * 768 + c] + A.pp[(64 + r) * 768 + c]
                         + A.pp[(128 + r) * 768 + c] + A.pp[(192 + r) * 768 + c];
                A.out_es[r * 768 + c] = de + s4 * (1.f / 256.f);
            } else if (c < 2560) {
                A.out_qg[r * 1024 + (c - 1536)] = gate_f(v + A.qg_b[c - 1536]);
            } else {
                A.out_kg[r * 1024 + (c - 2560)] = gate_f(v + A.kg_b[c - 2560]);
            }
        }
    } else {
        int m = blk - 32;                 // 0..223
        int ct = m % 28, s = m / 28;      // 8 slices
        if (ct < 12) {
            const float* pA = A.partA; const float* b1 = A.eff_b1;
            auto xl = [&](int r, int k) {      // eh = gelu(eln@eff_w1 + b1), lazily
                float v = b1[k];
#pragma unroll
                for (int q = 0; q < 4; ++q) v += pA[(size_t)(q * 64 + r) * 3584 + 768 + k];
                return gelu_f(v);
            };
            gemm_tile(xl, A.eff_w2, 768, ct * 64, s * 96, 96, A.partB, 1792, ct * 64, s, xs, wt);
        } else {
            const float* pA = A.partA; const float* ppp = A.pp; const float* db = A.delta_b;
            auto xl = [&](int r, int k) {      // e_shifted = pool + delta_e, lazily
                float v = db[k];
#pragma unroll
                for (int q = 0; q < 4; ++q) v += pA[(size_t)(q * 64 + r) * 3584 + k];
                float s4 = ppp[r * 768 + k] + ppp[(64 + r) * 768 + k]
                         + ppp[(128 + r) * 768 + k] + ppp[(192 + r) * 768 + k];
                return v + s4 * (1.f / 256.f);
            };
            gemm_tile(xl, A.u_w, 1024, (ct - 12) * 64, s * 96, 96, A.partB, 1792, ct * 64, s, xs, wt);
        }
    }
    grid.sync();

    // ================= S6: effect_pred epilogue (blocks 0..31) || wu with lazy u (blocks 32..127) =================
    if (blk < 32) {
#pragma unroll
        for (int ii = 0; ii < 6; ++ii) {
            int idx = blk * TPB + t + ii * 8192;   // 64*768 = 49152 = 6*8192
            int r = idx / 768, c = idx - r * 768;
            float v = A.eff_b2[c];
#pragma unroll
            for (int q = 0; q < 8; ++q) v += A.partB[(size_t)(q * 64 + r) * 1792 + c];
            A.out_ep[r * 768 + c] = v;
        }
    } else if (blk < 128) {
        int m = blk - 32;                  // 0..95
        int h = m / 12, ctile = m % 12;
        for (int n = t; n < 8192; n += TPB) {
            int b = n >> 7, d = n & 127;
            float v = 0.f;
#pragma unroll
            for (int q = 0; q < 8; ++q) v += A.partB[(size_t)(q * 64 + b) * 1792 + 768 + h * 128 + d];
            smem[b * 132 + d] = v;         // u[b, h*128+d]
        }
        __syncthreads();
        int c = ctile * 64 + (t >> 2);
        int bo = t & 3;
        const float* vr = A.v_w + (size_t)c * 1024 + h * 128;
        float acc[16];
#pragma unroll
        for (int i = 0; i < 16; ++i) acc[i] = 0.f;
        for (int d = 0; d < 128; d += 4) {
            float4 w4 = *(const float4*)(vr + d);
#pragma unroll
            for (int i = 0; i < 16; ++i) {
                const float* ub = &smem[(4 * i + bo) * 132 + d];
                acc[i] += w4.x * ub[0] + w4.y * ub[1] + w4.z * ub[2] + w4.w * ub[3];
            }
        }
#pragma unroll
        for (int i = 0; i < 16; ++i) {
            int b = 4 * i + bo;
            A.wu[(b * 8 + h) * 768 + c] = acc[i];
        }
    }
}

// ============ bias_s[b][h][k] = scale * tok_cause[b,k,:] . wu[b,h,:] ============
__global__ __launch_bounds__(256) void k_bias2(const float* __restrict__ tok_cause, const float* __restrict__ wu,
                        const float* __restrict__ ls_ptr, float* __restrict__ bias_s)
{
    int b = blockIdx.x, kt = blockIdx.y;
    __shared__ float wuh[8][768];
    for (int n = threadIdx.x; n < 6144; n += TPB)
        ((float*)wuh)[n] = wu[b * 6144 + n];
    __syncthreads();
    const int lane = threadIdx.x & 63, w = threadIdx.x >> 6;
    float4 wur[3][8];
#pragma unroll
    for (int j = 0; j < 3; ++j)
#pragma unroll
        for (int h = 0; h < 8; ++h)
            wur[j][h] = *(const float4*)&wuh[h][(lane + 64 * j) * 4];
    float scale = expf(ls_ptr[0]) * 0.08838834764831845f;
#pragma unroll
    for (int rr = 0; rr < 4; ++rr) {
        int row = kt * 16 + w * 4 + rr;
        const float4* tr = (const float4*)(tok_cause + ((size_t)b * 256 + row) * 768);
        float4 t0 = tr[lane], t1 = tr[lane + 64], t2 = tr[lane + 128];
        float acc[8];
#pragma unroll
        for (int h = 0; h < 8; ++h) {
            acc[h] = t0.x * wur[0][h].x + t0.y * wur[0][h].y + t0.z * wur[0][h].z + t0.w * wur[0][h].w
                   + t1.x * wur[1][h].x + t1.y * wur[1][h].y + t1.z * wur[1][h].z + t1.w * wur[1][h].w
                   + t2.x * wur[2][h].x + t2.y * wur[2][h].y + t2.z * wur[2][h].z + t2.w * wur[2][h].w;
        }
#pragma unroll
        for (int h = 0; h < 8; ++h) {
            float vv = acc[h];
#pragma unroll
            for (int o_ = 32; o_ > 0; o_ >>= 1) vv += __shfl_xor(vv, o_);
            if (lane == 0) bias_s[(b * 8 + h) * 256 + row] = vv * scale;
        }
    }
}

// ============ broadcast logit_bias[b,h,q,k] = bias_s[b,h,k] ============
__global__ __launch_bounds__(256) void k_broadcast(const float* __restrict__ bias_s, float* __restrict__ out)
{
    const vf4* b4 = (const vf4*)bias_s;
    vf4* o4 = (vf4*)out;
    unsigned i = blockIdx.x * TPB + threadIdx.x;
#pragma unroll
    for (int j = 0; j < 16; ++j) {
        unsigned idx = i + (unsigned)j * (2048u * TPB);
        vf4 v = b4[(idx >> 14) * 64 + (idx & 63)];
        __builtin_nontemporal_store(v, &o4[idx]);
    }
}

extern "C" void kernel_launch(void* const* d_in, const int* in_sizes, int n_in,
                              void* d_out, int out_size, void* d_ws, size_t ws_size,
                              hipStream_t stream)
{
    (void)in_sizes; (void)n_in; (void)out_size; (void)ws_size;
    const float* tok_cause  = (const float*)d_in[2];
    const float* logit_sc   = (const float*)d_in[26];

    float* ws = (float*)d_ws;
    float* cat_ln = ws + 0;        // 98304
    float* ctx    = ws + 98304;    // 49152
    float* dln    = ws + 147456;   // 49152
    float* eln    = ws + 196608;   // 49152
    float* pp     = ws + 245760;   // 196608
    float* wu     = ws + 442368;   // 393216
    float* bias_s = ws + 835584;   // 131072  (end 966656 floats = 3.9 MB)

    float* out    = (float*)d_out;
    float* out_qg = out + 0;
    float* out_kg = out + 65536;
    float* out_es = out + 131072;
    float* out_de = out + 180224;
    float* out_lb = out + 229376;
    float* out_ep = out + 33783808;

    // split-K partial buffers live in the tail of logit_bias (overwritten last by k_broadcast)
    float* pbase = out_lb + 20000000;
    float* part1 = pbase;             // 12*64*768  = 589824
    float* part2 = pbase + 589824;    // 12*64*768  = 589824
    float* partA = pbase + 1179648;   //  4*64*3584 = 917504
    float* partB = pbase + 2097152;   //  8*64*1792 = 917504  (end 3.01M < 13.3M spare)

    CoopArgs A;
    A.ec = (const float*)d_in[0];  A.ea = (const float*)d_in[1];
    A.fln_g = (const float*)d_in[4]; A.fln_b = (const float*)d_in[5];
    A.tok_effect = (const float*)d_in[3];
    A.fuse_w1 = (const float*)d_in[6];  A.fuse_b1 = (const float*)d_in[7];
    A.fuse_w2 = (const float*)d_in[8];  A.fuse_b2 = (const float*)d_in[9];
    A.delta_ln_g = (const float*)d_in[10]; A.delta_ln_b = (const float*)d_in[11];
    A.eff_ln_g = (const float*)d_in[18];   A.eff_ln_b = (const float*)d_in[19];
    A.delta_w = (const float*)d_in[12]; A.delta_b = (const float*)d_in[13];
    A.eff_w1 = (const float*)d_in[20];  A.eff_b1 = (const float*)d_in[21];
    A.eff_w2 = (const float*)d_in[22];  A.eff_b2 = (const float*)d_in[23];
    A.qg_w = (const float*)d_in[14]; A.qg_b = (const float*)d_in[15];
    A.kg_w = (const float*)d_in[16]; A.kg_b = (const float*)d_in[17];
    A.u_w = (const float*)d_in[24];  A.v_w = (const float*)d_in[25];
    A.cat_ln = cat_ln; A.ctx = ctx; A.dln = dln; A.eln = eln; A.pp = pp; A.wu = wu;
    A.part1 = part1; A.part2 = part2; A.partA = partA; A.partB = partB;
    A.out_de = out_de; A.out_es = out_es; A.out_qg = out_qg; A.out_kg = out_kg; A.out_ep = out_ep;

    void* kargs[] = { (void*)&A };
    hipLaunchCooperativeKernel((const void*)k_coop, dim3(256), dim3(TPB), kargs, 0, stream);

    k_bias2<<<dim3(64, 16), TPB, 0, stream>>>(tok_cause, wu, logit_sc, bias_s);
    k_broadcast<<<2048, TPB, 0, stream>>>(bias_s, out_lb);
}

// Round 4
// 186.942 us; speedup vs baseline: 1.8999x; 1.8999x over previous
//
#include <hip/hip_runtime.h>
#include <math.h>

#define TPB 256

typedef float vf4 __attribute__((ext_vector_type(4)));

__device__ __forceinline__ float gelu_f(float x) {
    return 0.5f * x * (1.0f + erff(x * 0.70710678118654752f));
}
__device__ __forceinline__ float gate_f(float x) {
    float si = x / (1.0f + expf(-x));
    return 1.0f + tanhf(si);
}

// ---- 64x64 output tile, one K-slice of split-K GEMM; X via loader functor ----
// LDS: xs[64][33] row-major (bank-conflict-free store: bank=(r+k)%32), wt[32][68].
template <class XL>
__device__ __forceinline__ void gemm_tile(XL xload, const float* __restrict__ W, int Wld, int cb,
                                          int k0, int kslice, float* part, int totN, int gcol, int s,
                                          float* __restrict__ xs, float* __restrict__ wt)
{
    const int t = threadIdx.x;
    const int tr4 = (t >> 4) << 2;
    const int tc4 = (t & 15) << 2;
    float acc[4][4] = {{0.f,0.f,0.f,0.f},{0.f,0.f,0.f,0.f},{0.f,0.f,0.f,0.f},{0.f,0.f,0.f,0.f}};
    for (int kc = 0; kc < kslice; kc += 32) {
        for (int n = t; n < 2048; n += TPB) {
            int r = n >> 5, k = n & 31;              // coalesced global: lanes -> consecutive k
            xs[r * 33 + k] = xload(r, k0 + kc + k);  // store bank=(r+k)%32: conflict-free
        }
        for (int n = t; n < 2048; n += TPB) {
            int k = n >> 6, c = n & 63;
            wt[k * 68 + c] = W[(size_t)(k0 + kc + k) * Wld + cb + c];
        }
        __syncthreads();
#pragma unroll
        for (int k = 0; k < 32; ++k) {
            float x0 = xs[(tr4 + 0) * 33 + k];
            float x1 = xs[(tr4 + 1) * 33 + k];
            float x2 = xs[(tr4 + 2) * 33 + k];
            float x3 = xs[(tr4 + 3) * 33 + k];
            float4 wv = *(const float4*)&wt[k * 68 + tc4];
            acc[0][0] += x0 * wv.x; acc[0][1] += x0 * wv.y; acc[0][2] += x0 * wv.z; acc[0][3] += x0 * wv.w;
            acc[1][0] += x1 * wv.x; acc[1][1] += x1 * wv.y; acc[1][2] += x1 * wv.z; acc[1][3] += x1 * wv.w;
            acc[2][0] += x2 * wv.x; acc[2][1] += x2 * wv.y; acc[2][2] += x2 * wv.z; acc[2][3] += x2 * wv.w;
            acc[3][0] += x3 * wv.x; acc[3][1] += x3 * wv.y; acc[3][2] += x3 * wv.z; acc[3][3] += x3 * wv.w;
        }
        __syncthreads();
    }
    float* pp = part + (size_t)(s * 64 + tr4) * totN + gcol + tc4;
#pragma unroll
    for (int i = 0; i < 4; ++i)
#pragma unroll
        for (int j = 0; j < 4; ++j)
            pp[i * totN + j] = acc[i][j];
}

#define GEMM_LDS __shared__ float xs[64 * 33]; __shared__ float wt[32 * 68];

// ============ front: concat-LN (blocks 0..63) + pool1 partials (blocks 64..831) ============
__global__ __launch_bounds__(256) void k_front(const float* __restrict__ ec, const float* __restrict__ ea,
                        const float* __restrict__ g, const float* __restrict__ bb,
                        float* __restrict__ o,
                        const float* __restrict__ tok_effect, float* __restrict__ pp)
{
    int t = threadIdx.x;
    if (blockIdx.x < 64) {
        int r = blockIdx.x;
        __shared__ float red[4];
        float v[6]; float sum = 0.f;
#pragma unroll
        for (int j = 0; j < 6; ++j) {
            int c = t + j * TPB;
            float x = (c < 768) ? ec[r * 768 + c] : ea[r * 768 + (c - 768)];
            v[j] = x; sum += x;
        }
#pragma unroll
        for (int o_ = 32; o_ > 0; o_ >>= 1) sum += __shfl_xor(sum, o_);
        if ((t & 63) == 0) red[t >> 6] = sum;
        __syncthreads();
        sum = red[0] + red[1] + red[2] + red[3];
        float mean = sum * (1.f / 1536.f);
        __syncthreads();
        float s2 = 0.f;
#pragma unroll
        for (int j = 0; j < 6; ++j) { float d = v[j] - mean; s2 += d * d; }
#pragma unroll
        for (int o_ = 32; o_ > 0; o_ >>= 1) s2 += __shfl_xor(s2, o_);
        if ((t & 63) == 0) red[t >> 6] = s2;
        __syncthreads();
        s2 = red[0] + red[1] + red[2] + red[3];
        float rstd = rsqrtf(s2 * (1.f / 1536.f) + 1e-5f);
#pragma unroll
        for (int j = 0; j < 6; ++j) {
            int c = t + j * TPB;
            o[r * 1536 + c] = (v[j] - mean) * rstd * g[c] + bb[c];
        }
    } else {
        int m = blockIdx.x - 64;           // 0..767
        int cch = m % 3, b = (m / 3) % 64, qz = m / 192;
        int c = cch * TPB + t;
        const float* base = tok_effect + (size_t)(b * 256 + qz * 64) * 768 + c;
        float s = 0.f;
#pragma unroll 16
        for (int q = 0; q < 64; ++q) s += base[(size_t)q * 768];
        pp[(qz * 64 + b) * 768 + c] = s;
    }
}

// ============ g1: cat_ln @ fuse_w1 -> part1 (12 ct x 8 s, kslice=192) ============
__global__ __launch_bounds__(256) void k_g1(const float* __restrict__ cat_ln, const float* __restrict__ w1,
                                            float* __restrict__ part1)
{
    GEMM_LDS;
    int ct = blockIdx.x % 12, s = blockIdx.x / 12;
    auto xl = [&](int r, int k) { return cat_ln[r * 1536 + k]; };
    gemm_tile(xl, w1, 768, ct * 64, s * 192, 192, part1, 768, ct * 64, s, xs, wt);
}

// ============ g2: gelu(sum part1 + b1) @ fuse_w2 -> part2 (12 ct x 8 s, kslice=96) ============
__global__ __launch_bounds__(256) void k_g2(const float* __restrict__ part1, const float* __restrict__ b1,
                                            const float* __restrict__ w2, float* __restrict__ part2)
{
    GEMM_LDS;
    int ct = blockIdx.x % 12, s = blockIdx.x / 12;
    auto xl = [&](int r, int k) {
        float v = b1[k];
#pragma unroll
        for (int q = 0; q < 8; ++q) v += part1[(size_t)(q * 64 + r) * 768 + k];
        return gelu_f(v);
    };
    gemm_tile(xl, w2, 768, ct * 64, s * 96, 96, part2, 768, ct * 64, s, xs, wt);
}

// ============ ln: ctx = sum part2 + b2; dual LN -> dln, eln ============
__global__ __launch_bounds__(256) void k_ln(const float* __restrict__ part2, const float* __restrict__ b2,
                        const float* __restrict__ dg, const float* __restrict__ db,
                        const float* __restrict__ eg, const float* __restrict__ eb,
                        float* __restrict__ ctx, float* __restrict__ od, float* __restrict__ oe)
{
    int r = blockIdx.x, t = threadIdx.x;
    __shared__ float red[4];
    float v[3]; float sum = 0.f;
#pragma unroll
    for (int j = 0; j < 3; ++j) {
        int c = t + j * TPB;
        float x = b2[c];
#pragma unroll
        for (int s = 0; s < 8; ++s) x += part2[(size_t)(s * 64 + r) * 768 + c];
        v[j] = x; sum += x;
        ctx[r * 768 + c] = x;
    }
#pragma unroll
    for (int o_ = 32; o_ > 0; o_ >>= 1) sum += __shfl_xor(sum, o_);
    if ((t & 63) == 0) red[t >> 6] = sum;
    __syncthreads();
    sum = red[0] + red[1] + red[2] + red[3];
    float mean = sum * (1.f / 768.f);
    __syncthreads();
    float s2 = 0.f;
#pragma unroll
    for (int j = 0; j < 3; ++j) { float d = v[j] - mean; s2 += d * d; }
#pragma unroll
    for (int o_ = 32; o_ > 0; o_ >>= 1) s2 += __shfl_xor(s2, o_);
    if ((t & 63) == 0) red[t >> 6] = s2;
    __syncthreads();
    s2 = red[0] + red[1] + red[2] + red[3];
    float rstd = rsqrtf(s2 * (1.f / 768.f) + 1e-5f);
#pragma unroll
    for (int j = 0; j < 3; ++j) {
        int c = t + j * TPB;
        float xh = (v[j] - mean) * rstd;
        od[r * 768 + c] = xh * dg[c] + db[c];
        oe[r * 768 + c] = xh * eg[c] + eb[c];
    }
}

// ============ gA: delta|eff1|qg|kg partials (56 ct x 4 s, kslice=192) ============
struct GAArgs {
    const float *dln, *eln, *ctx, *delta_w, *eff_w1, *qg_w, *kg_w;
    float* partA;
};
__global__ __launch_bounds__(256) void k_gA(GAArgs A)
{
    GEMM_LDS;
    int ct = blockIdx.x % 56, s = blockIdx.x / 56;
    const float* X; const float* W; int Wld, cb;
    if (ct < 12)      { X = A.dln; W = A.delta_w; Wld = 768;  cb = ct * 64; }
    else if (ct < 24) { X = A.eln; W = A.eff_w1;  Wld = 768;  cb = (ct - 12) * 64; }
    else if (ct < 40) { X = A.ctx; W = A.qg_w;    Wld = 1024; cb = (ct - 24) * 64; }
    else              { X = A.ctx; W = A.kg_w;    Wld = 1024; cb = (ct - 40) * 64; }
    auto xl = [&](int r, int k) { return X[r * 768 + k]; };
    gemm_tile(xl, W, Wld, cb, s * 192, 192, A.partA, 3584, ct * 64, s, xs, wt);
}

// ============ mid: batchA outputs (blocks 0..27) || batchB partials (blocks 28..251) ============
struct MidArgs {
    const float *partA, *pp, *delta_b, *eff_b1, *qg_b, *kg_b, *eff_w2, *u_w;
    float *partB, *out_de, *out_es, *out_qg, *out_kg;
};
__global__ __launch_bounds__(256) void k_mid(MidArgs A)
{
    GEMM_LDS;
    const int t = threadIdx.x;
    if (blockIdx.x < 28) {
#pragma unroll
        for (int ii = 0; ii < 32; ++ii) {
            int idx = blockIdx.x * TPB + t + ii * 7168;     // 64*3584 = 229376 = 28*256*32
            int r = idx / 3584, c = idx - r * 3584;
            if (c >= 768 && c < 1536) continue;             // eff1: consumed lazily, no output
            float v = A.partA[(size_t)r * 3584 + c] + A.partA[(size_t)(64 + r) * 3584 + c]
                    + A.partA[(size_t)(128 + r) * 3584 + c] + A.partA[(size_t)(192 + r) * 3584 + c];
            if (c < 768) {
                float de = v + A.delta_b[c];
                A.out_de[r * 768 + c] = de;
                float s4 = A.pp[r * 768 + c] + A.pp[(64 + r) * 768 + c]
                         + A.pp[(128 + r) * 768 + c] + A.pp[(192 + r) * 768 + c];
                A.out_es[r * 768 + c] = de + s4 * (1.f / 256.f);
            } else if (c < 2560) {
                A.out_qg[r * 1024 + (c - 1536)] = gate_f(v + A.qg_b[c - 1536]);
            } else {
                A.out_kg[r * 1024 + (c - 2560)] = gate_f(v + A.kg_b[c - 2560]);
            }
        }
    } else {
        int m = blockIdx.x - 28;              // 0..223
        int ct = m % 28, s = m / 28;          // 8 slices, kslice=96
        if (ct < 12) {
            auto xl = [&](int r, int k) {     // eh = gelu(eln@eff_w1 + b1), lazily from partA
                float v = A.eff_b1[k];
#pragma unroll
                for (int q = 0; q < 4; ++q) v += A.partA[(size_t)(q * 64 + r) * 3584 + 768 + k];
                return gelu_f(v);
            };
            gemm_tile(xl, A.eff_w2, 768, ct * 64, s * 96, 96, A.partB, 1792, ct * 64, s, xs, wt);
        } else {
            auto xl = [&](int r, int k) {     // e_shifted = delta_e + pooled, lazily
                float v = A.delta_b[k];
#pragma unroll
                for (int q = 0; q < 4; ++q) v += A.partA[(size_t)(q * 64 + r) * 3584 + k];
                float s4 = A.pp[r * 768 + k] + A.pp[(64 + r) * 768 + k]
                         + A.pp[(128 + r) * 768 + k] + A.pp[(192 + r) * 768 + k];
                return v + s4 * (1.f / 256.f);
            };
            gemm_tile(xl, A.u_w, 1024, (ct - 12) * 64, s * 96, 96, A.partB, 1792, ct * 64, s, xs, wt);
        }
    }
}

// ============ tail: effect_pred epilogue (blocks 0..5) || wu (blocks 6..101) ============
__global__ __launch_bounds__(256) void k_tail(const float* __restrict__ partB, const float* __restrict__ eff_b2,
                                              const float* __restrict__ v_w,
                                              float* __restrict__ out_ep, float* __restrict__ wu)
{
    const int t = threadIdx.x;
    if (blockIdx.x < 6) {
#pragma unroll
        for (int ii = 0; ii < 32; ++ii) {
            int idx = blockIdx.x * TPB + t + ii * 1536;    // 64*768 = 49152 = 6*256*32
            int r = idx / 768, c = idx - r * 768;
            float v = eff_b2[c];
#pragma unroll
            for (int q = 0; q < 8; ++q) v += partB[(size_t)(q * 64 + r) * 1792 + c];
            out_ep[r * 768 + c] = v;
        }
    } else {
        __shared__ float us[64 * 132];
        int m = blockIdx.x - 6;                 // 0..95
        int h = m / 12, ctile = m % 12;
        for (int n = t; n < 8192; n += TPB) {
            int b = n >> 7, d = n & 127;
            float v = 0.f;
#pragma unroll
            for (int q = 0; q < 8; ++q) v += partB[(size_t)(q * 64 + b) * 1792 + 768 + h * 128 + d];
            us[b * 132 + d] = v;                // u[b, h*128+d]
        }
        __syncthreads();
        int c = ctile * 64 + (t >> 2);
        int bo = t & 3;
        const float* vr = v_w + (size_t)c * 1024 + h * 128;
        float acc[16];
#pragma unroll
        for (int i = 0; i < 16; ++i) acc[i] = 0.f;
        for (int d = 0; d < 128; d += 4) {
            float4 w4 = *(const float4*)(vr + d);
#pragma unroll
            for (int i = 0; i < 16; ++i) {
                const float* ub = &us[(4 * i + bo) * 132 + d];
                acc[i] += w4.x * ub[0] + w4.y * ub[1] + w4.z * ub[2] + w4.w * ub[3];
            }
        }
#pragma unroll
        for (int i = 0; i < 16; ++i) {
            int b = 4 * i + bo;
            wu[(b * 8 + h) * 768 + c] = acc[i];
        }
    }
}

// ============ bias_s[b][h][k] = scale * tok_cause[b,k,:] . wu[b,h,:] ============
__global__ __launch_bounds__(256) void k_bias2(const float* __restrict__ tok_cause, const float* __restrict__ wu,
                        const float* __restrict__ ls_ptr, float* __restrict__ bias_s)
{
    int b = blockIdx.x, kt = blockIdx.y;
    __shared__ float wuh[8][768];
    for (int n = threadIdx.x; n < 6144; n += TPB)
        ((float*)wuh)[n] = wu[b * 6144 + n];
    __syncthreads();
    const int lane = threadIdx.x & 63, w = threadIdx.x >> 6;
    float4 wur[3][8];
#pragma unroll
    for (int j = 0; j < 3; ++j)
#pragma unroll
        for (int h = 0; h < 8; ++h)
            wur[j][h] = *(const float4*)&wuh[h][(lane + 64 * j) * 4];
    float scale = expf(ls_ptr[0]) * 0.08838834764831845f;
#pragma unroll
    for (int rr = 0; rr < 4; ++rr) {
        int row = kt * 16 + w * 4 + rr;
        const float4* tr = (const float4*)(tok_cause + ((size_t)b * 256 + row) * 768);
        float4 t0 = tr[lane], t1 = tr[lane + 64], t2 = tr[lane + 128];
        float acc[8];
#pragma unroll
        for (int h = 0; h < 8; ++h) {
            acc[h] = t0.x * wur[0][h].x + t0.y * wur[0][h].y + t0.z * wur[0][h].z + t0.w * wur[0][h].w
                   + t1.x * wur[1][h].x + t1.y * wur[1][h].y + t1.z * wur[1][h].z + t1.w * wur[1][h].w
                   + t2.x * wur[2][h].x + t2.y * wur[2][h].y + t2.z * wur[2][h].z + t2.w * wur[2][h].w;
        }
#pragma unroll
        for (int h = 0; h < 8; ++h) {
            float vv = acc[h];
#pragma unroll
            for (int o_ = 32; o_ > 0; o_ >>= 1) vv += __shfl_xor(vv, o_);
            if (lane == 0) bias_s[(b * 8 + h) * 256 + row] = vv * scale;
        }
    }
}

// ============ broadcast logit_bias[b,h,q,k] = bias_s[b,h,k] ============
__global__ __launch_bounds__(256) void k_broadcast(const float* __restrict__ bias_s, float* __restrict__ out)
{
    const vf4* b4 = (const vf4*)bias_s;
    vf4* o4 = (vf4*)out;
    unsigned i = blockIdx.x * TPB + threadIdx.x;
#pragma unroll
    for (int j = 0; j < 16; ++j) {
        unsigned idx = i + (unsigned)j * (2048u * TPB);
        vf4 v = b4[(idx >> 14) * 64 + (idx & 63)];
        __builtin_nontemporal_store(v, &o4[idx]);
    }
}

extern "C" void kernel_launch(void* const* d_in, const int* in_sizes, int n_in,
                              void* d_out, int out_size, void* d_ws, size_t ws_size,
                              hipStream_t stream)
{
    (void)in_sizes; (void)n_in; (void)out_size; (void)ws_size;
    const float* emb_cause  = (const float*)d_in[0];
    const float* emb_action = (const float*)d_in[1];
    const float* tok_cause  = (const float*)d_in[2];
    const float* tok_effect = (const float*)d_in[3];
    const float* fuse_ln_g  = (const float*)d_in[4];
    const float* fuse_ln_b  = (const float*)d_in[5];
    const float* fuse_w1    = (const float*)d_in[6];
    const float* fuse_b1    = (const float*)d_in[7];
    const float* fuse_w2    = (const float*)d_in[8];
    const float* fuse_b2    = (const float*)d_in[9];
    const float* delta_ln_g = (const float*)d_in[10];
    const float* delta_ln_b = (const float*)d_in[11];
    const float* delta_w    = (const float*)d_in[12];
    const float* delta_b    = (const float*)d_in[13];
    const float* qg_w       = (const float*)d_in[14];
    const float* qg_b       = (const float*)d_in[15];
    const float* kg_w       = (const float*)d_in[16];
    const float* kg_b       = (const float*)d_in[17];
    const float* eff_ln_g   = (const float*)d_in[18];
    const float* eff_ln_b   = (const float*)d_in[19];
    const float* eff_w1     = (const float*)d_in[20];
    const float* eff_b1     = (const float*)d_in[21];
    const float* eff_w2     = (const float*)d_in[22];
    const float* eff_b2     = (const float*)d_in[23];
    const float* u_w        = (const float*)d_in[24];
    const float* v_w        = (const float*)d_in[25];
    const float* logit_sc   = (const float*)d_in[26];

    float* ws = (float*)d_ws;
    float* cat_ln = ws + 0;        // 98304
    float* ctx    = ws + 98304;    // 49152
    float* dln    = ws + 147456;   // 49152
    float* eln    = ws + 196608;   // 49152
    float* pp     = ws + 245760;   // 196608
    float* wu     = ws + 442368;   // 393216
    float* bias_s = ws + 835584;   // 131072  (end 966656 floats = 3.9 MB)

    float* out    = (float*)d_out;
    float* out_qg = out + 0;
    float* out_kg = out + 65536;
    float* out_es = out + 131072;
    float* out_de = out + 180224;
    float* out_lb = out + 229376;
    float* out_ep = out + 33783808;

    // split-K partial buffers in the tail of logit_bias (overwritten last by k_broadcast)
    float* pbase = out_lb + 20000000;
    float* part1 = pbase;             // 8*64*768  = 393216
    float* part2 = pbase + 393216;    // 8*64*768  = 393216
    float* partA = pbase + 786432;    // 4*64*3584 = 917504
    float* partB = pbase + 1703936;   // 8*64*1792 = 917504  (end 2.62M, well inside 13.3M spare)

    // 1) concat-LN + pool1 partials
    k_front<<<832, TPB, 0, stream>>>(emb_cause, emb_action, fuse_ln_g, fuse_ln_b, cat_ln,
                                     tok_effect, pp);
    // 2) fuse1 partials
    k_g1<<<96, TPB, 0, stream>>>(cat_ln, fuse_w1, part1);
    // 3) fuse2 partials (lazy GELU-epilogue of fuse1)
    k_g2<<<96, TPB, 0, stream>>>(part1, fuse_b1, fuse_w2, part2);
    // 4) ctx + dual LN
    k_ln<<<64, TPB, 0, stream>>>(part2, fuse_b2, delta_ln_g, delta_ln_b,
                                 eff_ln_g, eff_ln_b, ctx, dln, eln);
    // 5) batchA partials: delta | eff1 | qg | kg
    {
        GAArgs A; A.dln = dln; A.eln = eln; A.ctx = ctx;
        A.delta_w = delta_w; A.eff_w1 = eff_w1; A.qg_w = qg_w; A.kg_w = kg_w; A.partA = partA;
        k_gA<<<224, TPB, 0, stream>>>(A);
    }
    // 6) batchA outputs (de, es, qg, kg) || batchB partials (eff2 w/ lazy eh, u_w w/ lazy es)
    {
        MidArgs M; M.partA = partA; M.pp = pp;
        M.delta_b = delta_b; M.eff_b1 = eff_b1; M.qg_b = qg_b; M.kg_b = kg_b;
        M.eff_w2 = eff_w2; M.u_w = u_w; M.partB = partB;
        M.out_de = out_de; M.out_es = out_es; M.out_qg = out_qg; M.out_kg = out_kg;
        k_mid<<<252, TPB, 0, stream>>>(M);
    }
    // 7) effect_pred epilogue || wu fold (lazy u from partB)
    k_tail<<<102, TPB, 0, stream>>>(partB, eff_b2, v_w, out_ep, wu);
    // 8) per-(b,h,k) bias
    k_bias2<<<dim3(64, 16), TPB, 0, stream>>>(tok_cause, wu, logit_sc, bias_s);
    // 9) broadcast
    k_broadcast<<<2048, TPB, 0, stream>>>(bias_s, out_lb);
}

// Round 5
// 172.696 us; speedup vs baseline: 2.0566x; 1.0825x over previous
//
#include <hip/hip_runtime.h>
#include <math.h>

#define TPB 256

typedef float vf4 __attribute__((ext_vector_type(4)));

__device__ __forceinline__ float gelu_f(float x) {
    return 0.5f * x * (1.0f + erff(x * 0.70710678118654752f));
}
__device__ __forceinline__ float gate_f(float x) {
    float si = x / (1.0f + expf(-x));
    return 1.0f + tanhf(si);
}

// ---- 64x64 output tile, one K-slice of split-K GEMM; X via loader functor ----
// LDS: xs[32][68] k-major (store bank=(4k+r)%32: 4-way, cheap; float4 read at
// k*68+tr4: 16B-aligned broadcast, conflict-free). wt[32][68] as before.
template <class XL>
__device__ __forceinline__ void gemm_tile(XL xload, const float* __restrict__ W, int Wld, int cb,
                                          int k0, int kslice, float* part, int totN, int gcol, int s,
                                          float* __restrict__ xs, float* __restrict__ wt)
{
    const int t = threadIdx.x;
    const int tr4 = (t >> 4) << 2;
    const int tc4 = (t & 15) << 2;
    float acc[4][4] = {{0.f,0.f,0.f,0.f},{0.f,0.f,0.f,0.f},{0.f,0.f,0.f,0.f},{0.f,0.f,0.f,0.f}};
    for (int kc = 0; kc < kslice; kc += 32) {
        for (int n = t; n < 2048; n += TPB) {
            int r = n >> 5, k = n & 31;              // lanes -> consecutive k: coalesced xload
            xs[k * 68 + r] = xload(r, k0 + kc + k);  // store: 4-way bank conflict only
        }
        for (int n = t; n < 2048; n += TPB) {
            int k = n >> 6, c = n & 63;
            wt[k * 68 + c] = W[(size_t)(k0 + kc + k) * Wld + cb + c];
        }
        __syncthreads();
#pragma unroll
        for (int k = 0; k < 32; ++k) {
            float4 xv = *(const float4*)&xs[k * 68 + tr4];
            float4 wv = *(const float4*)&wt[k * 68 + tc4];
            acc[0][0] += xv.x * wv.x; acc[0][1] += xv.x * wv.y; acc[0][2] += xv.x * wv.z; acc[0][3] += xv.x * wv.w;
            acc[1][0] += xv.y * wv.x; acc[1][1] += xv.y * wv.y; acc[1][2] += xv.y * wv.z; acc[1][3] += xv.y * wv.w;
            acc[2][0] += xv.z * wv.x; acc[2][1] += xv.z * wv.y; acc[2][2] += xv.z * wv.z; acc[2][3] += xv.z * wv.w;
            acc[3][0] += xv.w * wv.x; acc[3][1] += xv.w * wv.y; acc[3][2] += xv.w * wv.z; acc[3][3] += xv.w * wv.w;
        }
        __syncthreads();
    }
    float* pp = part + (size_t)(s * 64 + tr4) * totN + gcol + tc4;
#pragma unroll
    for (int i = 0; i < 4; ++i)
#pragma unroll
        for (int j = 0; j < 4; ++j)
            pp[i * totN + j] = acc[i][j];
}

#define GEMM_LDS __shared__ float xs[32 * 68]; __shared__ float wt[32 * 68];

// ============ front: concat-LN (blocks 0..63) + pool1 partials (blocks 64..831) ============
__global__ __launch_bounds__(256) void k_front(const float* __restrict__ ec, const float* __restrict__ ea,
                        const float* __restrict__ g, const float* __restrict__ bb,
                        float* __restrict__ o,
                        const float* __restrict__ tok_effect, float* __restrict__ pp)
{
    int t = threadIdx.x;
    if (blockIdx.x < 64) {
        int r = blockIdx.x;
        __shared__ float red[4];
        float v[6]; float sum = 0.f;
#pragma unroll
        for (int j = 0; j < 6; ++j) {
            int c = t + j * TPB;
            float x = (c < 768) ? ec[r * 768 + c] : ea[r * 768 + (c - 768)];
            v[j] = x; sum += x;
        }
#pragma unroll
        for (int o_ = 32; o_ > 0; o_ >>= 1) sum += __shfl_xor(sum, o_);
        if ((t & 63) == 0) red[t >> 6] = sum;
        __syncthreads();
        sum = red[0] + red[1] + red[2] + red[3];
        float mean = sum * (1.f / 1536.f);
        __syncthreads();
        float s2 = 0.f;
#pragma unroll
        for (int j = 0; j < 6; ++j) { float d = v[j] - mean; s2 += d * d; }
#pragma unroll
        for (int o_ = 32; o_ > 0; o_ >>= 1) s2 += __shfl_xor(s2, o_);
        if ((t & 63) == 0) red[t >> 6] = s2;
        __syncthreads();
        s2 = red[0] + red[1] + red[2] + red[3];
        float rstd = rsqrtf(s2 * (1.f / 1536.f) + 1e-5f);
#pragma unroll
        for (int j = 0; j < 6; ++j) {
            int c = t + j * TPB;
            o[r * 1536 + c] = (v[j] - mean) * rstd * g[c] + bb[c];
        }
    } else {
        int m = blockIdx.x - 64;           // 0..767
        int cch = m % 3, b = (m / 3) % 64, qz = m / 192;
        int c = cch * TPB + t;
        const float* base = tok_effect + (size_t)(b * 256 + qz * 64) * 768 + c;
        float s = 0.f;
#pragma unroll 16
        for (int q = 0; q < 64; ++q) s += base[(size_t)q * 768];
        pp[(qz * 64 + b) * 768 + c] = s;
    }
}

// ============ g1: cat_ln @ fuse_w1 -> part1 (12 ct x 12 s, kslice=128) ============
__global__ __launch_bounds__(256) void k_g1(const float* __restrict__ cat_ln, const float* __restrict__ w1,
                                            float* __restrict__ part1)
{
    GEMM_LDS;
    int ct = blockIdx.x % 12, s = blockIdx.x / 12;
    auto xl = [&](int r, int k) { return cat_ln[r * 1536 + k]; };
    gemm_tile(xl, w1, 768, ct * 64, s * 128, 128, part1, 768, ct * 64, s, xs, wt);
}

// ============ g2: gelu(sum part1 + b1) @ fuse_w2 -> part2 (12 ct x 12 s, kslice=64) ============
__global__ __launch_bounds__(256) void k_g2(const float* __restrict__ part1, const float* __restrict__ b1,
                                            const float* __restrict__ w2, float* __restrict__ part2)
{
    GEMM_LDS;
    int ct = blockIdx.x % 12, s = blockIdx.x / 12;
    auto xl = [&](int r, int k) {
        float v = b1[k];
#pragma unroll
        for (int q = 0; q < 12; ++q) v += part1[(size_t)(q * 64 + r) * 768 + k];
        return gelu_f(v);
    };
    gemm_tile(xl, w2, 768, ct * 64, s * 64, 64, part2, 768, ct * 64, s, xs, wt);
}

// ============ ln: ctx = sum part2 + b2; dual LN -> dln, eln ============
__global__ __launch_bounds__(256) void k_ln(const float* __restrict__ part2, const float* __restrict__ b2,
                        const float* __restrict__ dg, const float* __restrict__ db,
                        const float* __restrict__ eg, const float* __restrict__ eb,
                        float* __restrict__ ctx, float* __restrict__ od, float* __restrict__ oe)
{
    int r = blockIdx.x, t = threadIdx.x;
    __shared__ float red[4];
    float v[3]; float sum = 0.f;
#pragma unroll
    for (int j = 0; j < 3; ++j) {
        int c = t + j * TPB;
        float x = b2[c];
#pragma unroll
        for (int s = 0; s < 12; ++s) x += part2[(size_t)(s * 64 + r) * 768 + c];
        v[j] = x; sum += x;
        ctx[r * 768 + c] = x;
    }
#pragma unroll
    for (int o_ = 32; o_ > 0; o_ >>= 1) sum += __shfl_xor(sum, o_);
    if ((t & 63) == 0) red[t >> 6] = sum;
    __syncthreads();
    sum = red[0] + red[1] + red[2] + red[3];
    float mean = sum * (1.f / 768.f);
    __syncthreads();
    float s2 = 0.f;
#pragma unroll
    for (int j = 0; j < 3; ++j) { float d = v[j] - mean; s2 += d * d; }
#pragma unroll
    for (int o_ = 32; o_ > 0; o_ >>= 1) s2 += __shfl_xor(s2, o_);
    if ((t & 63) == 0) red[t >> 6] = s2;
    __syncthreads();
    s2 = red[0] + red[1] + red[2] + red[3];
    float rstd = rsqrtf(s2 * (1.f / 768.f) + 1e-5f);
#pragma unroll
    for (int j = 0; j < 3; ++j) {
        int c = t + j * TPB;
        float xh = (v[j] - mean) * rstd;
        od[r * 768 + c] = xh * dg[c] + db[c];
        oe[r * 768 + c] = xh * eg[c] + eb[c];
    }
}

// ============ gA: delta|eff1|qg|kg partials (56 ct x 8 s, kslice=96) ============
struct GAArgs {
    const float *dln, *eln, *ctx, *delta_w, *eff_w1, *qg_w, *kg_w;
    float* partA;
};
__global__ __launch_bounds__(256) void k_gA(GAArgs A)
{
    GEMM_LDS;
    int ct = blockIdx.x % 56, s = blockIdx.x / 56;
    const float* X; const float* W; int Wld, cb;
    if (ct < 12)      { X = A.dln; W = A.delta_w; Wld = 768;  cb = ct * 64; }
    else if (ct < 24) { X = A.eln; W = A.eff_w1;  Wld = 768;  cb = (ct - 12) * 64; }
    else if (ct < 40) { X = A.ctx; W = A.qg_w;    Wld = 1024; cb = (ct - 24) * 64; }
    else              { X = A.ctx; W = A.kg_w;    Wld = 1024; cb = (ct - 40) * 64; }
    auto xl = [&](int r, int k) { return X[r * 768 + k]; };
    gemm_tile(xl, W, Wld, cb, s * 96, 96, A.partA, 3584, ct * 64, s, xs, wt);
}

// ============ mid: batchA outputs (blocks 0..27) || batchB partials (blocks 28..251) ============
struct MidArgs {
    const float *partA, *pp, *delta_b, *eff_b1, *qg_b, *kg_b, *eff_w2, *u_w;
    float *partB, *out_de, *out_es, *out_qg, *out_kg;
};
__global__ __launch_bounds__(256) void k_mid(MidArgs A)
{
    GEMM_LDS;
    const int t = threadIdx.x;
    if (blockIdx.x < 28) {
#pragma unroll
        for (int ii = 0; ii < 32; ++ii) {
            int idx = blockIdx.x * TPB + t + ii * 7168;     // 64*3584 = 229376 = 28*256*32
            int r = idx / 3584, c = idx - r * 3584;
            if (c >= 768 && c < 1536) continue;             // eff1: consumed lazily, no output
            float v = 0.f;
#pragma unroll
            for (int q = 0; q < 8; ++q) v += A.partA[(size_t)(q * 64 + r) * 3584 + c];
            if (c < 768) {
                float de = v + A.delta_b[c];
                A.out_de[r * 768 + c] = de;
                float s4 = A.pp[r * 768 + c] + A.pp[(64 + r) * 768 + c]
                         + A.pp[(128 + r) * 768 + c] + A.pp[(192 + r) * 768 + c];
                A.out_es[r * 768 + c] = de + s4 * (1.f / 256.f);
            } else if (c < 2560) {
                A.out_qg[r * 1024 + (c - 1536)] = gate_f(v + A.qg_b[c - 1536]);
            } else {
                A.out_kg[r * 1024 + (c - 2560)] = gate_f(v + A.kg_b[c - 2560]);
            }
        }
    } else {
        int m = blockIdx.x - 28;              // 0..223
        int ct = m % 28, s = m / 28;          // 8 slices, kslice=96
        if (ct < 12) {
            auto xl = [&](int r, int k) {     // eh = gelu(eln@eff_w1 + b1), lazily from partA
                float v = A.eff_b1[k];
#pragma unroll
                for (int q = 0; q < 8; ++q) v += A.partA[(size_t)(q * 64 + r) * 3584 + 768 + k];
                return gelu_f(v);
            };
            gemm_tile(xl, A.eff_w2, 768, ct * 64, s * 96, 96, A.partB, 1792, ct * 64, s, xs, wt);
        } else {
            auto xl = [&](int r, int k) {     // e_shifted = delta_e + pooled, lazily
                float v = A.delta_b[k];
#pragma unroll
                for (int q = 0; q < 8; ++q) v += A.partA[(size_t)(q * 64 + r) * 3584 + k];
                float s4 = A.pp[r * 768 + k] + A.pp[(64 + r) * 768 + k]
                         + A.pp[(128 + r) * 768 + k] + A.pp[(192 + r) * 768 + k];
                return v + s4 * (1.f / 256.f);
            };
            gemm_tile(xl, A.u_w, 1024, (ct - 12) * 64, s * 96, 96, A.partB, 1792, ct * 64, s, xs, wt);
        }
    }
}

// ============ tail: effect_pred epilogue (blocks 0..5) || wu (blocks 6..101) ============
__global__ __launch_bounds__(256) void k_tail(const float* __restrict__ partB, const float* __restrict__ eff_b2,
                                              const float* __restrict__ v_w,
                                              float* __restrict__ out_ep, float* __restrict__ wu)
{
    const int t = threadIdx.x;
    if (blockIdx.x < 6) {
#pragma unroll
        for (int ii = 0; ii < 32; ++ii) {
            int idx = blockIdx.x * TPB + t + ii * 1536;    // 64*768 = 49152 = 6*256*32
            int r = idx / 768, c = idx - r * 768;
            float v = eff_b2[c];
#pragma unroll
            for (int q = 0; q < 8; ++q) v += partB[(size_t)(q * 64 + r) * 1792 + c];
            out_ep[r * 768 + c] = v;
        }
    } else {
        __shared__ float us[64 * 132];
        int m = blockIdx.x - 6;                 // 0..95
        int h = m / 12, ctile = m % 12;
        for (int n = t; n < 8192; n += TPB) {
            int b = n >> 7, d = n & 127;
            float v = 0.f;
#pragma unroll
            for (int q = 0; q < 8; ++q) v += partB[(size_t)(q * 64 + b) * 1792 + 768 + h * 128 + d];
            us[b * 132 + d] = v;                // u[b, h*128+d]
        }
        __syncthreads();
        int c = ctile * 64 + (t >> 2);
        int bo = t & 3;
        const float* vr = v_w + (size_t)c * 1024 + h * 128;
        float acc[16];
#pragma unroll
        for (int i = 0; i < 16; ++i) acc[i] = 0.f;
        for (int d = 0; d < 128; d += 4) {
            float4 w4 = *(const float4*)(vr + d);
#pragma unroll
            for (int i = 0; i < 16; ++i) {
                const float* ub = &us[(4 * i + bo) * 132 + d];
                acc[i] += w4.x * ub[0] + w4.y * ub[1] + w4.z * ub[2] + w4.w * ub[3];
            }
        }
#pragma unroll
        for (int i = 0; i < 16; ++i) {
            int b = 4 * i + bo;
            wu[(b * 8 + h) * 768 + c] = acc[i];
        }
    }
}

// ============ fused bias + broadcast ============
// grid (64 b, 8 kt): per block compute bias[b, 0..7h, 32 k-rows], then write the
// q-broadcast directly: logit_bias[b,h,q,kt*32..+31], 128 B contiguous per (h,q).
__global__ __launch_bounds__(256) void k_biasbc(const float* __restrict__ tok_cause, const float* __restrict__ wu,
                         const float* __restrict__ ls_ptr, float* __restrict__ out_lb)
{
    int b = blockIdx.x, kt = blockIdx.y;
    __shared__ float wuh[8 * 768];     // 24 KB
    __shared__ float bsm[8 * 32];      // bias values [h][k_local]
    for (int n = threadIdx.x; n < 6144; n += TPB)
        wuh[n] = wu[b * 6144 + n];
    __syncthreads();
    const int lane = threadIdx.x & 63, w = threadIdx.x >> 6;
    float4 wur[3][8];
#pragma unroll
    for (int j = 0; j < 3; ++j)
#pragma unroll
        for (int h = 0; h < 8; ++h)
            wur[j][h] = *(const float4*)&wuh[h * 768 + (lane + 64 * j) * 4];
    float scale = expf(ls_ptr[0]) * 0.08838834764831845f;
#pragma unroll
    for (int rr = 0; rr < 8; ++rr) {
        int rl = w * 8 + rr;                    // 0..31 local k-row
        int row = kt * 32 + rl;
        const float4* tr = (const float4*)(tok_cause + ((size_t)b * 256 + row) * 768);
        float4 t0 = tr[lane], t1 = tr[lane + 64], t2 = tr[lane + 128];
        float acc[8];
#pragma unroll
        for (int h = 0; h < 8; ++h) {
            acc[h] = t0.x * wur[0][h].x + t0.y * wur[0][h].y + t0.z * wur[0][h].z + t0.w * wur[0][h].w
                   + t1.x * wur[1][h].x + t1.y * wur[1][h].y + t1.z * wur[1][h].z + t1.w * wur[1][h].w
                   + t2.x * wur[2][h].x + t2.y * wur[2][h].y + t2.z * wur[2][h].z + t2.w * wur[2][h].w;
        }
#pragma unroll
        for (int h = 0; h < 8; ++h) {
            float vv = acc[h];
#pragma unroll
            for (int o_ = 32; o_ > 0; o_ >>= 1) vv += __shfl_xor(vv, o_);
            if (lane == 0) bsm[h * 32 + rl] = vv * scale;
        }
    }
    __syncthreads();
    // broadcast: 2048 (h,q) segments x 32 k floats = 8 vf4 each
    const vf4* bs4 = (const vf4*)bsm;          // [8][8]
    vf4* o4 = (vf4*)out_lb;
    int v = threadIdx.x & 7, sq0 = threadIdx.x >> 3;   // 32 segments per pass
#pragma unroll
    for (int it = 0; it < 64; ++it) {
        int seg = sq0 + it * 32;               // 0..2047 = h*256 + q
        int h = seg >> 8, q = seg & 255;
        vf4 val = bs4[h * 8 + v];
        __builtin_nontemporal_store(val, &o4[(((size_t)(b * 8 + h) * 256 + q) << 6) + kt * 8 + v]);
    }
}

extern "C" void kernel_launch(void* const* d_in, const int* in_sizes, int n_in,
                              void* d_out, int out_size, void* d_ws, size_t ws_size,
                              hipStream_t stream)
{
    (void)in_sizes; (void)n_in; (void)out_size; (void)ws_size;
    const float* emb_cause  = (const float*)d_in[0];
    const float* emb_action = (const float*)d_in[1];
    const float* tok_cause  = (const float*)d_in[2];
    const float* tok_effect = (const float*)d_in[3];
    const float* fuse_ln_g  = (const float*)d_in[4];
    const float* fuse_ln_b  = (const float*)d_in[5];
    const float* fuse_w1    = (const float*)d_in[6];
    const float* fuse_b1    = (const float*)d_in[7];
    const float* fuse_w2    = (const float*)d_in[8];
    const float* fuse_b2    = (const float*)d_in[9];
    const float* delta_ln_g = (const float*)d_in[10];
    const float* delta_ln_b = (const float*)d_in[11];
    const float* delta_w    = (const float*)d_in[12];
    const float* delta_b    = (const float*)d_in[13];
    const float* qg_w       = (const float*)d_in[14];
    const float* qg_b       = (const float*)d_in[15];
    const float* kg_w       = (const float*)d_in[16];
    const float* kg_b       = (const float*)d_in[17];
    const float* eff_ln_g   = (const float*)d_in[18];
    const float* eff_ln_b   = (const float*)d_in[19];
    const float* eff_w1     = (const float*)d_in[20];
    const float* eff_b1     = (const float*)d_in[21];
    const float* eff_w2     = (const float*)d_in[22];
    const float* eff_b2     = (const float*)d_in[23];
    const float* u_w        = (const float*)d_in[24];
    const float* v_w        = (const float*)d_in[25];
    const float* logit_sc   = (const float*)d_in[26];

    float* ws = (float*)d_ws;
    float* cat_ln = ws + 0;        // 98304
    float* ctx    = ws + 98304;    // 49152
    float* dln    = ws + 147456;   // 49152
    float* eln    = ws + 196608;   // 49152
    float* pp     = ws + 245760;   // 196608
    float* wu     = ws + 442368;   // 393216 (end 835584 floats = 3.3 MB)

    float* out    = (float*)d_out;
    float* out_qg = out + 0;
    float* out_kg = out + 65536;
    float* out_es = out + 131072;
    float* out_de = out + 180224;
    float* out_lb = out + 229376;
    float* out_ep = out + 33783808;

    // split-K partial buffers in the tail of logit_bias (overwritten last by k_biasbc)
    float* pbase = out_lb + 20000000;
    float* part1 = pbase;             // 12*64*768 = 589824
    float* part2 = pbase + 589824;    // 12*64*768 = 589824
    float* partA = pbase + 1179648;   //  8*64*3584 = 1835008
    float* partB = pbase + 3014656;   //  8*64*1792 = 917504 (end 3.93M < 13.3M spare)

    // 1) concat-LN + pool1 partials
    k_front<<<832, TPB, 0, stream>>>(emb_cause, emb_action, fuse_ln_g, fuse_ln_b, cat_ln,
                                     tok_effect, pp);
    // 2) fuse1 partials (12 slices)
    k_g1<<<144, TPB, 0, stream>>>(cat_ln, fuse_w1, part1);
    // 3) fuse2 partials (lazy GELU-epilogue of fuse1; 12 slices)
    k_g2<<<144, TPB, 0, stream>>>(part1, fuse_b1, fuse_w2, part2);
    // 4) ctx + dual LN
    k_ln<<<64, TPB, 0, stream>>>(part2, fuse_b2, delta_ln_g, delta_ln_b,
                                 eff_ln_g, eff_ln_b, ctx, dln, eln);
    // 5) batchA partials: delta | eff1 | qg | kg (8 slices, 448 blocks)
    {
        GAArgs A; A.dln = dln; A.eln = eln; A.ctx = ctx;
        A.delta_w = delta_w; A.eff_w1 = eff_w1; A.qg_w = qg_w; A.kg_w = kg_w; A.partA = partA;
        k_gA<<<448, TPB, 0, stream>>>(A);
    }
    // 6) batchA outputs || batchB partials (eff2 w/ lazy eh, u_w w/ lazy e_shifted)
    {
        MidArgs M; M.partA = partA; M.pp = pp;
        M.delta_b = delta_b; M.eff_b1 = eff_b1; M.qg_b = qg_b; M.kg_b = kg_b;
        M.eff_w2 = eff_w2; M.u_w = u_w; M.partB = partB;
        M.out_de = out_de; M.out_es = out_es; M.out_qg = out_qg; M.out_kg = out_kg;
        k_mid<<<252, TPB, 0, stream>>>(M);
    }
    // 7) effect_pred epilogue || wu fold (lazy u from partB)
    k_tail<<<102, TPB, 0, stream>>>(partB, eff_b2, v_w, out_ep, wu);
    // 8) fused per-(b,h,k) bias + q-broadcast
    k_biasbc<<<dim3(64, 8), TPB, 0, stream>>>(tok_cause, wu, logit_sc, out_lb);
}

// Round 6
// 143.863 us; speedup vs baseline: 2.4688x; 1.2004x over previous
//
#include <hip/hip_runtime.h>
#include <math.h>

#define TPB 256

typedef float vf4 __attribute__((ext_vector_type(4)));

__device__ __forceinline__ float gelu_f(float x) {
    return 0.5f * x * (1.0f + erff(x * 0.70710678118654752f));
}
__device__ __forceinline__ float gate_f(float x) {
    float si = x / (1.0f + expf(-x));
    return 1.0f + tanhf(si);
}

// ---- 64x64 output tile, one K-slice of split-K GEMM; X via loader functor ----
// Double-buffered: prefetch chunk i+1 (global->regs) overlaps chunk i FMAs.
// LDS: xs[32][68] k-major (store 4-way conflict only; float4 read broadcast,
// conflict-free). wt[32][68].
template <class XL>
__device__ __forceinline__ void gemm_tile(XL xload, const float* __restrict__ W, int Wld, int cb,
                                          int k0, int kslice, float* part, int totN, int gcol, int s,
                                          float* __restrict__ xs, float* __restrict__ wt)
{
    const int t = threadIdx.x;
    const int tr4 = (t >> 4) << 2;
    const int tc4 = (t & 15) << 2;
    const int a  = t >> 5, kk = t & 31;      // X staging: element (r = a+8j, k = kk)
    const int wk = t >> 6, wc = t & 63;      // W staging: element (krow = wk+4j, c = wc)
    float xv[8], wv[8];
#pragma unroll
    for (int j = 0; j < 8; ++j) {
        xv[j] = xload(a + 8 * j, k0 + kk);
        wv[j] = W[(size_t)(k0 + wk + 4 * j) * Wld + cb + wc];
    }
    float acc[4][4] = {{0.f,0.f,0.f,0.f},{0.f,0.f,0.f,0.f},{0.f,0.f,0.f,0.f},{0.f,0.f,0.f,0.f}};
    for (int kc = 0; kc < kslice; kc += 32) {
#pragma unroll
        for (int j = 0; j < 8; ++j) {
            xs[kk * 68 + a + 8 * j] = xv[j];
            wt[(wk + 4 * j) * 68 + wc] = wv[j];
        }
        __syncthreads();
        int kn = kc + 32;
        if (kn < kslice) {                   // prefetch next chunk during FMAs
#pragma unroll
            for (int j = 0; j < 8; ++j) {
                xv[j] = xload(a + 8 * j, k0 + kn + kk);
                wv[j] = W[(size_t)(k0 + kn + wk + 4 * j) * Wld + cb + wc];
            }
        }
#pragma unroll
        for (int k = 0; k < 32; ++k) {
            float4 xq = *(const float4*)&xs[k * 68 + tr4];
            float4 wq = *(const float4*)&wt[k * 68 + tc4];
            acc[0][0] += xq.x * wq.x; acc[0][1] += xq.x * wq.y; acc[0][2] += xq.x * wq.z; acc[0][3] += xq.x * wq.w;
            acc[1][0] += xq.y * wq.x; acc[1][1] += xq.y * wq.y; acc[1][2] += xq.y * wq.z; acc[1][3] += xq.y * wq.w;
            acc[2][0] += xq.z * wq.x; acc[2][1] += xq.z * wq.y; acc[2][2] += xq.z * wq.z; acc[2][3] += xq.z * wq.w;
            acc[3][0] += xq.w * wq.x; acc[3][1] += xq.w * wq.y; acc[3][2] += xq.w * wq.z; acc[3][3] += xq.w * wq.w;
        }
        __syncthreads();
    }
    float* pp = part + (size_t)(s * 64 + tr4) * totN + gcol + tc4;
#pragma unroll
    for (int i = 0; i < 4; ++i)
#pragma unroll
        for (int j = 0; j < 4; ++j)
            pp[i * totN + j] = acc[i][j];
}

#define GEMM_LDS __shared__ float xs[32 * 68]; __shared__ float wt[32 * 68];

// ============ front: cat-LN stats (blocks 0..63) + pool1 partials (64..831) ============
// stats1[r] = {mean, rstd} over concat(ec[r], ea[r]) (1536)
__global__ __launch_bounds__(256) void k_front(const float* __restrict__ ec, const float* __restrict__ ea,
                        float* __restrict__ stats1,
                        const float* __restrict__ tok_effect, float* __restrict__ pp)
{
    int t = threadIdx.x;
    if (blockIdx.x < 64) {
        int r = blockIdx.x;
        __shared__ float red[4];
        float v[6]; float sum = 0.f;
#pragma unroll
        for (int j = 0; j < 6; ++j) {
            int c = t + j * TPB;
            float x = (c < 768) ? ec[r * 768 + c] : ea[r * 768 + (c - 768)];
            v[j] = x; sum += x;
        }
#pragma unroll
        for (int o_ = 32; o_ > 0; o_ >>= 1) sum += __shfl_xor(sum, o_);
        if ((t & 63) == 0) red[t >> 6] = sum;
        __syncthreads();
        sum = red[0] + red[1] + red[2] + red[3];
        float mean = sum * (1.f / 1536.f);
        __syncthreads();
        float s2 = 0.f;
#pragma unroll
        for (int j = 0; j < 6; ++j) { float d = v[j] - mean; s2 += d * d; }
#pragma unroll
        for (int o_ = 32; o_ > 0; o_ >>= 1) s2 += __shfl_xor(s2, o_);
        if ((t & 63) == 0) red[t >> 6] = s2;
        __syncthreads();
        s2 = red[0] + red[1] + red[2] + red[3];
        if (t == 0) {
            stats1[2 * r]     = mean;
            stats1[2 * r + 1] = rsqrtf(s2 * (1.f / 1536.f) + 1e-5f);
        }
    } else {
        int m = blockIdx.x - 64;           // 0..767
        int cch = m % 3, b = (m / 3) % 64, qz = m / 192;
        int c = cch * TPB + t;
        const float* base = tok_effect + (size_t)(b * 256 + qz * 64) * 768 + c;
        float s = 0.f;
#pragma unroll 16
        for (int q = 0; q < 64; ++q) s += base[(size_t)q * 768];
        pp[(qz * 64 + b) * 768 + c] = s;
    }
}

// ============ g1: LN(cat)@fuse_w1 -> part1 (12 ct x 12 s, kslice=128), lazy-LN X ============
struct G1Args {
    const float *ec, *ea, *stats1, *flg, *flb, *w1;
    float* part1;
};
__global__ __launch_bounds__(256) void k_g1(G1Args A)
{
    GEMM_LDS;
    int ct = blockIdx.x % 12, s = blockIdx.x / 12;
    auto xl = [&](int r, int k) {
        float raw = (k < 768) ? A.ec[r * 768 + k] : A.ea[r * 768 + (k - 768)];
        float m = A.stats1[2 * r], rs = A.stats1[2 * r + 1];
        return (raw - m) * rs * A.flg[k] + A.flb[k];
    };
    gemm_tile(xl, A.w1, 768, ct * 64, s * 128, 128, A.part1, 768, ct * 64, s, xs, wt);
}

// ============ g2: gelu(sum part1 + b1) @ fuse_w2 -> part2 (12 ct x 12 s, kslice=64) ============
__global__ __launch_bounds__(256) void k_g2(const float* __restrict__ part1, const float* __restrict__ b1,
                                            const float* __restrict__ w2, float* __restrict__ part2)
{
    GEMM_LDS;
    int ct = blockIdx.x % 12, s = blockIdx.x / 12;
    auto xl = [&](int r, int k) {
        float v = b1[k];
#pragma unroll
        for (int q = 0; q < 12; ++q) v += part1[(size_t)(q * 64 + r) * 768 + k];
        return gelu_f(v);
    };
    gemm_tile(xl, w2, 768, ct * 64, s * 64, 64, part2, 768, ct * 64, s, xs, wt);
}

// ============ ln: ctx = sum part2 + b2 (materialized); stats2[r] = {mean, rstd} ============
__global__ __launch_bounds__(256) void k_ln(const float* __restrict__ part2, const float* __restrict__ b2,
                                            float* __restrict__ ctx, float* __restrict__ stats2)
{
    int r = blockIdx.x, t = threadIdx.x;
    __shared__ float red[4];
    float v[3]; float sum = 0.f;
#pragma unroll
    for (int j = 0; j < 3; ++j) {
        int c = t + j * TPB;
        float x = b2[c];
#pragma unroll
        for (int s = 0; s < 12; ++s) x += part2[(size_t)(s * 64 + r) * 768 + c];
        v[j] = x; sum += x;
        ctx[r * 768 + c] = x;
    }
#pragma unroll
    for (int o_ = 32; o_ > 0; o_ >>= 1) sum += __shfl_xor(sum, o_);
    if ((t & 63) == 0) red[t >> 6] = sum;
    __syncthreads();
    sum = red[0] + red[1] + red[2] + red[3];
    float mean = sum * (1.f / 768.f);
    __syncthreads();
    float s2 = 0.f;
#pragma unroll
    for (int j = 0; j < 3; ++j) { float d = v[j] - mean; s2 += d * d; }
#pragma unroll
    for (int o_ = 32; o_ > 0; o_ >>= 1) s2 += __shfl_xor(s2, o_);
    if ((t & 63) == 0) red[t >> 6] = s2;
    __syncthreads();
    s2 = red[0] + red[1] + red[2] + red[3];
    if (t == 0) {
        stats2[2 * r]     = mean;
        stats2[2 * r + 1] = rsqrtf(s2 * (1.f / 768.f) + 1e-5f);
    }
}

// ============ gA: delta|eff1|qg|kg partials (56 ct x 8 s, kslice=96), lazy-LN X ============
struct GAArgs {
    const float *ctx, *stats2, *dg, *db, *eg, *eb;
    const float *delta_w, *eff_w1, *qg_w, *kg_w;
    float* partA;
};
__global__ __launch_bounds__(256) void k_gA(GAArgs A)
{
    GEMM_LDS;
    int ct = blockIdx.x % 56, s = blockIdx.x / 56;
    if (ct < 12) {
        auto xl = [&](int r, int k) {
            float m = A.stats2[2 * r], rs = A.stats2[2 * r + 1];
            return (A.ctx[r * 768 + k] - m) * rs * A.dg[k] + A.db[k];
        };
        gemm_tile(xl, A.delta_w, 768, ct * 64, s * 96, 96, A.partA, 3584, ct * 64, s, xs, wt);
    } else if (ct < 24) {
        auto xl = [&](int r, int k) {
            float m = A.stats2[2 * r], rs = A.stats2[2 * r + 1];
            return (A.ctx[r * 768 + k] - m) * rs * A.eg[k] + A.eb[k];
        };
        gemm_tile(xl, A.eff_w1, 768, (ct - 12) * 64, s * 96, 96, A.partA, 3584, ct * 64, s, xs, wt);
    } else {
        auto xl = [&](int r, int k) { return A.ctx[r * 768 + k]; };
        const float* W = (ct < 40) ? A.qg_w : A.kg_w;
        int cb = (ct < 40) ? (ct - 24) * 64 : (ct - 40) * 64;
        gemm_tile(xl, W, 1024, cb, s * 96, 96, A.partA, 3584, ct * 64, s, xs, wt);
    }
}

// ============ mid: batchA outputs (blocks 0..27) || batchB partials (28..251) ============
struct MidArgs {
    const float *partA, *pp, *delta_b, *eff_b1, *qg_b, *kg_b, *eff_w2, *u_w;
    float *partB, *out_de, *out_es, *out_qg, *out_kg;
};
__global__ __launch_bounds__(256) void k_mid(MidArgs A)
{
    GEMM_LDS;
    const int t = threadIdx.x;
    if (blockIdx.x < 28) {
#pragma unroll
        for (int ii = 0; ii < 32; ++ii) {
            int idx = blockIdx.x * TPB + t + ii * 7168;     // 64*3584 = 28*256*32
            int r = idx / 3584, c = idx - r * 3584;
            if (c >= 768 && c < 1536) continue;             // eff1: consumed lazily
            float v = 0.f;
#pragma unroll
            for (int q = 0; q < 8; ++q) v += A.partA[(size_t)(q * 64 + r) * 3584 + c];
            if (c < 768) {
                float de = v + A.delta_b[c];
                A.out_de[r * 768 + c] = de;
                float s4 = A.pp[r * 768 + c] + A.pp[(64 + r) * 768 + c]
                         + A.pp[(128 + r) * 768 + c] + A.pp[(192 + r) * 768 + c];
                A.out_es[r * 768 + c] = de + s4 * (1.f / 256.f);
            } else if (c < 2560) {
                A.out_qg[r * 1024 + (c - 1536)] = gate_f(v + A.qg_b[c - 1536]);
            } else {
                A.out_kg[r * 1024 + (c - 2560)] = gate_f(v + A.kg_b[c - 2560]);
            }
        }
    } else {
        int m = blockIdx.x - 28;              // 0..223
        int ct = m % 28, s = m / 28;          // 8 slices, kslice=96
        if (ct < 12) {
            auto xl = [&](int r, int k) {     // eh = gelu(eln@eff_w1 + b1), lazily
                float v = A.eff_b1[k];
#pragma unroll
                for (int q = 0; q < 8; ++q) v += A.partA[(size_t)(q * 64 + r) * 3584 + 768 + k];
                return gelu_f(v);
            };
            gemm_tile(xl, A.eff_w2, 768, ct * 64, s * 96, 96, A.partB, 1792, ct * 64, s, xs, wt);
        } else {
            auto xl = [&](int r, int k) {     // e_shifted = delta_e + pooled, lazily
                float v = A.delta_b[k];
#pragma unroll
                for (int q = 0; q < 8; ++q) v += A.partA[(size_t)(q * 64 + r) * 3584 + k];
                float s4 = A.pp[r * 768 + k] + A.pp[(64 + r) * 768 + k]
                         + A.pp[(128 + r) * 768 + k] + A.pp[(192 + r) * 768 + k];
                return v + s4 * (1.f / 256.f);
            };
            gemm_tile(xl, A.u_w, 1024, (ct - 12) * 64, s * 96, 96, A.partB, 1792, ct * 64, s, xs, wt);
        }
    }
}

// ============ tail: effect_pred epilogue (blocks 0..5) || wu (blocks 6..101) ============
__global__ __launch_bounds__(256) void k_tail(const float* __restrict__ partB, const float* __restrict__ eff_b2,
                                              const float* __restrict__ v_w,
                                              float* __restrict__ out_ep, float* __restrict__ wu)
{
    const int t = threadIdx.x;
    if (blockIdx.x < 6) {
#pragma unroll
        for (int ii = 0; ii < 32; ++ii) {
            int idx = blockIdx.x * TPB + t + ii * 1536;    // 64*768 = 6*256*32
            int r = idx / 768, c = idx - r * 768;
            float v = eff_b2[c];
#pragma unroll
            for (int q = 0; q < 8; ++q) v += partB[(size_t)(q * 64 + r) * 1792 + c];
            out_ep[r * 768 + c] = v;
        }
    } else {
        __shared__ float us[64 * 132];
        int m = blockIdx.x - 6;                 // 0..95
        int h = m / 12, ctile = m % 12;
        for (int n = t; n < 8192; n += TPB) {
            int b = n >> 7, d = n & 127;
            float v = 0.f;
#pragma unroll
            for (int q = 0; q < 8; ++q) v += partB[(size_t)(q * 64 + b) * 1792 + 768 + h * 128 + d];
            us[b * 132 + d] = v;                // u[b, h*128+d]
        }
        __syncthreads();
        int c = ctile * 64 + (t >> 2);
        int bo = t & 3;
        const float* vr = v_w + (size_t)c * 1024 + h * 128;
        float acc[16];
#pragma unroll
        for (int i = 0; i < 16; ++i) acc[i] = 0.f;
        for (int d = 0; d < 128; d += 4) {
            float4 w4 = *(const float4*)(vr + d);
#pragma unroll
            for (int i = 0; i < 16; ++i) {
                const float* ub = &us[(4 * i + bo) * 132 + d];
                acc[i] += w4.x * ub[0] + w4.y * ub[1] + w4.z * ub[2] + w4.w * ub[3];
            }
        }
#pragma unroll
        for (int i = 0; i < 16; ++i) {
            int b = 4 * i + bo;
            wu[(b * 8 + h) * 768 + c] = acc[i];
        }
    }
}

// ============ fused bias + broadcast ============
__global__ __launch_bounds__(256) void k_biasbc(const float* __restrict__ tok_cause, const float* __restrict__ wu,
                         const float* __restrict__ ls_ptr, float* __restrict__ out_lb)
{
    int b = blockIdx.x, kt = blockIdx.y;
    __shared__ float wuh[8 * 768];     // 24 KB
    __shared__ float bsm[8 * 32];      // bias values [h][k_local]
    for (int n = threadIdx.x; n < 6144; n += TPB)
        wuh[n] = wu[b * 6144 + n];
    __syncthreads();
    const int lane = threadIdx.x & 63, w = threadIdx.x >> 6;
    float4 wur[3][8];
#pragma unroll
    for (int j = 0; j < 3; ++j)
#pragma unroll
        for (int h = 0; h < 8; ++h)
            wur[j][h] = *(const float4*)&wuh[h * 768 + (lane + 64 * j) * 4];
    float scale = expf(ls_ptr[0]) * 0.08838834764831845f;
#pragma unroll
    for (int rr = 0; rr < 8; ++rr) {
        int rl = w * 8 + rr;                    // 0..31 local k-row
        int row = kt * 32 + rl;
        const float4* tr = (const float4*)(tok_cause + ((size_t)b * 256 + row) * 768);
        float4 t0 = tr[lane], t1 = tr[lane + 64], t2 = tr[lane + 128];
        float acc[8];
#pragma unroll
        for (int h = 0; h < 8; ++h) {
            acc[h] = t0.x * wur[0][h].x + t0.y * wur[0][h].y + t0.z * wur[0][h].z + t0.w * wur[0][h].w
                   + t1.x * wur[1][h].x + t1.y * wur[1][h].y + t1.z * wur[1][h].z + t1.w * wur[1][h].w
                   + t2.x * wur[2][h].x + t2.y * wur[2][h].y + t2.z * wur[2][h].z + t2.w * wur[2][h].w;
        }
#pragma unroll
        for (int h = 0; h < 8; ++h) {
            float vv = acc[h];
#pragma unroll
            for (int o_ = 32; o_ > 0; o_ >>= 1) vv += __shfl_xor(vv, o_);
            if (lane == 0) bsm[h * 32 + rl] = vv * scale;
        }
    }
    __syncthreads();
    const vf4* bs4 = (const vf4*)bsm;          // [8][8]
    vf4* o4 = (vf4*)out_lb;
    int v = threadIdx.x & 7, sq0 = threadIdx.x >> 3;
#pragma unroll
    for (int it = 0; it < 64; ++it) {
        int seg = sq0 + it * 32;               // 0..2047 = h*256 + q
        int h = seg >> 8, q = seg & 255;
        vf4 val = bs4[h * 8 + v];
        __builtin_nontemporal_store(val, &o4[(((size_t)(b * 8 + h) * 256 + q) << 6) + kt * 8 + v]);
    }
}

extern "C" void kernel_launch(void* const* d_in, const int* in_sizes, int n_in,
                              void* d_out, int out_size, void* d_ws, size_t ws_size,
                              hipStream_t stream)
{
    (void)in_sizes; (void)n_in; (void)out_size; (void)ws_size;
    const float* emb_cause  = (const float*)d_in[0];
    const float* emb_action = (const float*)d_in[1];
    const float* tok_cause  = (const float*)d_in[2];
    const float* tok_effect = (const float*)d_in[3];
    const float* fuse_ln_g  = (const float*)d_in[4];
    const float* fuse_ln_b  = (const float*)d_in[5];
    const float* fuse_w1    = (const float*)d_in[6];
    const float* fuse_b1    = (const float*)d_in[7];
    const float* fuse_w2    = (const float*)d_in[8];
    const float* fuse_b2    = (const float*)d_in[9];
    const float* delta_ln_g = (const float*)d_in[10];
    const float* delta_ln_b = (const float*)d_in[11];
    const float* delta_w    = (const float*)d_in[12];
    const float* delta_b    = (const float*)d_in[13];
    const float* qg_w       = (const float*)d_in[14];
    const float* qg_b       = (const float*)d_in[15];
    const float* kg_w       = (const float*)d_in[16];
    const float* kg_b       = (const float*)d_in[17];
    const float* eff_ln_g   = (const float*)d_in[18];
    const float* eff_ln_b   = (const float*)d_in[19];
    const float* eff_w1     = (const float*)d_in[20];
    const float* eff_b1     = (const float*)d_in[21];
    const float* eff_w2     = (const float*)d_in[22];
    const float* eff_b2     = (const float*)d_in[23];
    const float* u_w        = (const float*)d_in[24];
    const float* v_w        = (const float*)d_in[25];
    const float* logit_sc   = (const float*)d_in[26];

    float* ws = (float*)d_ws;
    float* ctx    = ws + 0;        // 49152
    float* pp     = ws + 49152;    // 196608
    float* wu     = ws + 245760;   // 393216
    float* stats1 = ws + 638976;   // 128
    float* stats2 = ws + 639104;   // 128  (end 639232 floats = 2.6 MB)

    float* out    = (float*)d_out;
    float* out_qg = out + 0;
    float* out_kg = out + 65536;
    float* out_es = out + 131072;
    float* out_de = out + 180224;
    float* out_lb = out + 229376;
    float* out_ep = out + 33783808;

    // split-K partial buffers in the tail of logit_bias (overwritten last by k_biasbc)
    float* pbase = out_lb + 20000000;
    float* part1 = pbase;             // 12*64*768 = 589824
    float* part2 = pbase + 589824;    // 12*64*768 = 589824
    float* partA = pbase + 1179648;   //  8*64*3584 = 1835008
    float* partB = pbase + 3014656;   //  8*64*1792 = 917504 (end 3.93M < 13.3M spare)

    // 1) cat-LN stats + pool1 partials
    k_front<<<832, TPB, 0, stream>>>(emb_cause, emb_action, stats1, tok_effect, pp);
    // 2) fuse1 partials (lazy LN applied in loader)
    {
        G1Args A; A.ec = emb_cause; A.ea = emb_action; A.stats1 = stats1;
        A.flg = fuse_ln_g; A.flb = fuse_ln_b; A.w1 = fuse_w1; A.part1 = part1;
        k_g1<<<144, TPB, 0, stream>>>(A);
    }
    // 3) fuse2 partials (lazy GELU-epilogue of fuse1)
    k_g2<<<144, TPB, 0, stream>>>(part1, fuse_b1, fuse_w2, part2);
    // 4) ctx + LN stats
    k_ln<<<64, TPB, 0, stream>>>(part2, fuse_b2, ctx, stats2);
    // 5) batchA partials: delta | eff1 (lazy-LN) | qg | kg (raw ctx)
    {
        GAArgs A; A.ctx = ctx; A.stats2 = stats2;
        A.dg = delta_ln_g; A.db = delta_ln_b; A.eg = eff_ln_g; A.eb = eff_ln_b;
        A.delta_w = delta_w; A.eff_w1 = eff_w1; A.qg_w = qg_w; A.kg_w = kg_w; A.partA = partA;
        k_gA<<<448, TPB, 0, stream>>>(A);
    }
    // 6) batchA outputs || batchB partials (eff2 w/ lazy eh, u_w w/ lazy e_shifted)
    {
        MidArgs M; M.partA = partA; M.pp = pp;
        M.delta_b = delta_b; M.eff_b1 = eff_b1; M.qg_b = qg_b; M.kg_b = kg_b;
        M.eff_w2 = eff_w2; M.u_w = u_w; M.partB = partB;
        M.out_de = out_de; M.out_es = out_es; M.out_qg = out_qg; M.out_kg = out_kg;
        k_mid<<<252, TPB, 0, stream>>>(M);
    }
    // 7) effect_pred epilogue || wu fold (lazy u from partB)
    k_tail<<<102, TPB, 0, stream>>>(partB, eff_b2, v_w, out_ep, wu);
    // 8) fused per-(b,h,k) bias + q-broadcast
    k_biasbc<<<dim3(64, 8), TPB, 0, stream>>>(tok_cause, wu, logit_sc, out_lb);
}

// Round 8
// 140.774 us; speedup vs baseline: 2.5230x; 1.0219x over previous
//
#include <hip/hip_runtime.h>
#include <math.h>

#define TPB 256

typedef float vf4 __attribute__((ext_vector_type(4)));

__device__ __forceinline__ float gelu_f(float x) {
    return 0.5f * x * (1.0f + erff(x * 0.70710678118654752f));
}
__device__ __forceinline__ float gate_f(float x) {
    float si = x / (1.0f + expf(-x));
    return 1.0f + tanhf(si);
}

// ---- 64x64 output tile, one K-slice of split-K GEMM; X via loader functor ----
// Double-buffered: prefetch chunk i+1 (global->regs) overlaps chunk i FMAs.
// LDS: xs[32][68] k-major (store 4-way conflict only; float4 read broadcast,
// conflict-free). wt[32][68].
template <class XL>
__device__ __forceinline__ void gemm_tile(XL xload, const float* __restrict__ W, int Wld, int cb,
                                          int k0, int kslice, float* part, int totN, int gcol, int s,
                                          float* __restrict__ xs, float* __restrict__ wt)
{
    const int t = threadIdx.x;
    const int tr4 = (t >> 4) << 2;
    const int tc4 = (t & 15) << 2;
    const int a  = t >> 5, kk = t & 31;      // X staging: element (r = a+8j, k = kk)
    const int wk = t >> 6, wc = t & 63;      // W staging: element (krow = wk+4j, c = wc)
    float xv[8], wv[8];
#pragma unroll
    for (int j = 0; j < 8; ++j) {
        xv[j] = xload(a + 8 * j, k0 + kk);
        wv[j] = W[(size_t)(k0 + wk + 4 * j) * Wld + cb + wc];
    }
    float acc[4][4] = {{0.f,0.f,0.f,0.f},{0.f,0.f,0.f,0.f},{0.f,0.f,0.f,0.f},{0.f,0.f,0.f,0.f}};
    for (int kc = 0; kc < kslice; kc += 32) {
#pragma unroll
        for (int j = 0; j < 8; ++j) {
            xs[kk * 68 + a + 8 * j] = xv[j];
            wt[(wk + 4 * j) * 68 + wc] = wv[j];
        }
        __syncthreads();
        int kn = kc + 32;
        if (kn < kslice) {                   // prefetch next chunk during FMAs
#pragma unroll
            for (int j = 0; j < 8; ++j) {
                xv[j] = xload(a + 8 * j, k0 + kn + kk);
                wv[j] = W[(size_t)(k0 + kn + wk + 4 * j) * Wld + cb + wc];
            }
        }
#pragma unroll
        for (int k = 0; k < 32; ++k) {
            float4 xq = *(const float4*)&xs[k * 68 + tr4];
            float4 wq = *(const float4*)&wt[k * 68 + tc4];
            acc[0][0] += xq.x * wq.x; acc[0][1] += xq.x * wq.y; acc[0][2] += xq.x * wq.z; acc[0][3] += xq.x * wq.w;
            acc[1][0] += xq.y * wq.x; acc[1][1] += xq.y * wq.y; acc[1][2] += xq.y * wq.z; acc[1][3] += xq.y * wq.w;
            acc[2][0] += xq.z * wq.x; acc[2][1] += xq.z * wq.y; acc[2][2] += xq.z * wq.z; acc[2][3] += xq.z * wq.w;
            acc[3][0] += xq.w * wq.x; acc[3][1] += xq.w * wq.y; acc[3][2] += xq.w * wq.z; acc[3][3] += xq.w * wq.w;
        }
        __syncthreads();
    }
    float* pp = part + (size_t)(s * 64 + tr4) * totN + gcol + tc4;
#pragma unroll
    for (int i = 0; i < 4; ++i)
#pragma unroll
        for (int j = 0; j < 4; ++j)
            pp[i * totN + j] = acc[i][j];
}

#define GEMM_LDS __shared__ float xs[32 * 68]; __shared__ float wt[32 * 68];

// ---- pool1 partial task (m in 0..767): pp[(qz*64+b)*768+c] = sum over 64 q ----
__device__ __forceinline__ void pool_task(const float* __restrict__ tok_effect,
                                          float* __restrict__ pp, int m, int t)
{
    int cch = m % 3, b = (m / 3) % 64, qz = m / 192;
    int c = cch * TPB + t;
    const float* base = tok_effect + (size_t)(b * 256 + qz * 64) * 768 + c;
    float s = 0.f;
#pragma unroll 16
    for (int q = 0; q < 64; ++q) s += __builtin_nontemporal_load(base + (size_t)q * 768);
    pp[(qz * 64 + b) * 768 + c] = s;
}

// ============ stats: cat-LN stats only (64 blocks) ============
__global__ __launch_bounds__(256) void k_stats(const float* __restrict__ ec, const float* __restrict__ ea,
                                               float* __restrict__ stats1)
{
    int t = threadIdx.x, r = blockIdx.x;
    __shared__ float red[4];
    float v[6]; float sum = 0.f;
#pragma unroll
    for (int j = 0; j < 6; ++j) {
        int c = t + j * TPB;
        float x = (c < 768) ? ec[r * 768 + c] : ea[r * 768 + (c - 768)];
        v[j] = x; sum += x;
    }
#pragma unroll
    for (int o_ = 32; o_ > 0; o_ >>= 1) sum += __shfl_xor(sum, o_);
    if ((t & 63) == 0) red[t >> 6] = sum;
    __syncthreads();
    sum = red[0] + red[1] + red[2] + red[3];
    float mean = sum * (1.f / 1536.f);
    __syncthreads();
    float s2 = 0.f;
#pragma unroll
    for (int j = 0; j < 6; ++j) { float d = v[j] - mean; s2 += d * d; }
#pragma unroll
    for (int o_ = 32; o_ > 0; o_ >>= 1) s2 += __shfl_xor(s2, o_);
    if ((t & 63) == 0) red[t >> 6] = s2;
    __syncthreads();
    s2 = red[0] + red[1] + red[2] + red[3];
    if (t == 0) {
        stats1[2 * r]     = mean;
        stats1[2 * r + 1] = rsqrtf(s2 * (1.f / 1536.f) + 1e-5f);
    }
}

// ============ g1: LN(cat)@fuse_w1 -> part1 (blocks 0..143) || pool qz 0-1 (144..527) ============
struct G1Args {
    const float *ec, *ea, *stats1, *flg, *flb, *w1;
    const float *tok_effect;
    float *part1, *pp;
};
__global__ __launch_bounds__(256) void k_g1(G1Args A)
{
    GEMM_LDS;
    if (blockIdx.x >= 144) {
        pool_task(A.tok_effect, A.pp, blockIdx.x - 144, threadIdx.x);
        return;
    }
    int ct = blockIdx.x % 12, s = blockIdx.x / 12;
    auto xl = [&](int r, int k) {
        float raw = (k < 768) ? A.ec[r * 768 + k] : A.ea[r * 768 + (k - 768)];
        float m = A.stats1[2 * r], rs = A.stats1[2 * r + 1];
        return (raw - m) * rs * A.flg[k] + A.flb[k];
    };
    gemm_tile(xl, A.w1, 768, ct * 64, s * 128, 128, A.part1, 768, ct * 64, s, xs, wt);
}

// ============ g2: gelu(sum part1 + b1) @ fuse_w2 -> part2 (0..143) || pool qz 2-3 ============
struct G2Args {
    const float *part1, *b1, *w2;
    const float *tok_effect;
    float *part2, *pp;
};
__global__ __launch_bounds__(256) void k_g2(G2Args A)
{
    GEMM_LDS;
    if (blockIdx.x >= 144) {
        pool_task(A.tok_effect, A.pp, blockIdx.x - 144 + 384, threadIdx.x);
        return;
    }
    int ct = blockIdx.x % 12, s = blockIdx.x / 12;
    auto xl = [&](int r, int k) {
        float v = A.b1[k];
#pragma unroll
        for (int q = 0; q < 12; ++q) v += A.part1[(size_t)(q * 64 + r) * 768 + k];
        return gelu_f(v);
    };
    gemm_tile(xl, A.w2, 768, ct * 64, s * 64, 64, A.part2, 768, ct * 64, s, xs, wt);
}

// ============ ln: ctx = sum part2 + b2 (materialized); stats2[r] = {mean, rstd} ============
__global__ __launch_bounds__(256) void k_ln(const float* __restrict__ part2, const float* __restrict__ b2,
                                            float* __restrict__ ctx, float* __restrict__ stats2)
{
    int r = blockIdx.x, t = threadIdx.x;
    __shared__ float red[4];
    float v[3]; float sum = 0.f;
#pragma unroll
    for (int j = 0; j < 3; ++j) {
        int c = t + j * TPB;
        float x = b2[c];
#pragma unroll
        for (int s = 0; s < 12; ++s) x += part2[(size_t)(s * 64 + r) * 768 + c];
        v[j] = x; sum += x;
        ctx[r * 768 + c] = x;
    }
#pragma unroll
    for (int o_ = 32; o_ > 0; o_ >>= 1) sum += __shfl_xor(sum, o_);
    if ((t & 63) == 0) red[t >> 6] = sum;
    __syncthreads();
    sum = red[0] + red[1] + red[2] + red[3];
    float mean = sum * (1.f / 768.f);
    __syncthreads();
    float s2 = 0.f;
#pragma unroll
    for (int j = 0; j < 3; ++j) { float d = v[j] - mean; s2 += d * d; }
#pragma unroll
    for (int o_ = 32; o_ > 0; o_ >>= 1) s2 += __shfl_xor(s2, o_);
    if ((t & 63) == 0) red[t >> 6] = s2;
    __syncthreads();
    s2 = red[0] + red[1] + red[2] + red[3];
    if (t == 0) {
        stats2[2 * r]     = mean;
        stats2[2 * r + 1] = rsqrtf(s2 * (1.f / 768.f) + 1e-5f);
    }
}

// ============ gA: delta|eff1|qg|kg partials (56 ct x 8 s, kslice=96), lazy-LN X ============
struct GAArgs {
    const float *ctx, *stats2, *dg, *db, *eg, *eb;
    const float *delta_w, *eff_w1, *qg_w, *kg_w;
    float* partA;
};
__global__ __launch_bounds__(256) void k_gA(GAArgs A)
{
    GEMM_LDS;
    int ct = blockIdx.x % 56, s = blockIdx.x / 56;
    if (ct < 12) {
        auto xl = [&](int r, int k) {
            float m = A.stats2[2 * r], rs = A.stats2[2 * r + 1];
            return (A.ctx[r * 768 + k] - m) * rs * A.dg[k] + A.db[k];
        };
        gemm_tile(xl, A.delta_w, 768, ct * 64, s * 96, 96, A.partA, 3584, ct * 64, s, xs, wt);
    } else if (ct < 24) {
        auto xl = [&](int r, int k) {
            float m = A.stats2[2 * r], rs = A.stats2[2 * r + 1];
            return (A.ctx[r * 768 + k] - m) * rs * A.eg[k] + A.eb[k];
        };
        gemm_tile(xl, A.eff_w1, 768, (ct - 12) * 64, s * 96, 96, A.partA, 3584, ct * 64, s, xs, wt);
    } else {
        auto xl = [&](int r, int k) { return A.ctx[r * 768 + k]; };
        const float* W = (ct < 40) ? A.qg_w : A.kg_w;
        int cb = (ct < 40) ? (ct - 24) * 64 : (ct - 40) * 64;
        gemm_tile(xl, W, 1024, cb, s * 96, 96, A.partA, 3584, ct * 64, s, xs, wt);
    }
}

// ============ mid: batchA outputs (blocks 0..27) || batchB partials (28..251) ============
struct MidArgs {
    const float *partA, *pp, *delta_b, *eff_b1, *qg_b, *kg_b, *eff_w2, *u_w;
    float *partB, *out_de, *out_es, *out_qg, *out_kg;
};
__global__ __launch_bounds__(256) void k_mid(MidArgs A)
{
    GEMM_LDS;
    const int t = threadIdx.x;
    if (blockIdx.x < 28) {
#pragma unroll
        for (int ii = 0; ii < 32; ++ii) {
            int idx = blockIdx.x * TPB + t + ii * 7168;     // 64*3584 = 28*256*32
            int r = idx / 3584, c = idx - r * 3584;
            if (c >= 768 && c < 1536) continue;             // eff1: consumed lazily
            float v = 0.f;
#pragma unroll
            for (int q = 0; q < 8; ++q) v += A.partA[(size_t)(q * 64 + r) * 3584 + c];
            if (c < 768) {
                float de = v + A.delta_b[c];
                A.out_de[r * 768 + c] = de;
                float s4 = A.pp[r * 768 + c] + A.pp[(64 + r) * 768 + c]
                         + A.pp[(128 + r) * 768 + c] + A.pp[(192 + r) * 768 + c];
                A.out_es[r * 768 + c] = de + s4 * (1.f / 256.f);
            } else if (c < 2560) {
                A.out_qg[r * 1024 + (c - 1536)] = gate_f(v + A.qg_b[c - 1536]);
            } else {
                A.out_kg[r * 1024 + (c - 2560)] = gate_f(v + A.kg_b[c - 2560]);
            }
        }
    } else {
        int m = blockIdx.x - 28;              // 0..223
        int ct = m % 28, s = m / 28;          // 8 slices, kslice=96
        if (ct < 12) {
            auto xl = [&](int r, int k) {     // eh = gelu(eln@eff_w1 + b1), lazily
                float v = A.eff_b1[k];
#pragma unroll
                for (int q = 0; q < 8; ++q) v += A.partA[(size_t)(q * 64 + r) * 3584 + 768 + k];
                return gelu_f(v);
            };
            gemm_tile(xl, A.eff_w2, 768, ct * 64, s * 96, 96, A.partB, 1792, ct * 64, s, xs, wt);
        } else {
            auto xl = [&](int r, int k) {     // e_shifted = delta_e + pooled, lazily
                float v = A.delta_b[k];
#pragma unroll
                for (int q = 0; q < 8; ++q) v += A.partA[(size_t)(q * 64 + r) * 3584 + k];
                float s4 = A.pp[r * 768 + k] + A.pp[(64 + r) * 768 + k]
                         + A.pp[(128 + r) * 768 + k] + A.pp[(192 + r) * 768 + k];
                return v + s4 * (1.f / 256.f);
            };
            gemm_tile(xl, A.u_w, 1024, (ct - 12) * 64, s * 96, 96, A.partB, 1792, ct * 64, s, xs, wt);
        }
    }
}

// ============ tail: effect_pred epilogue (blocks 0..5) || wu (blocks 6..101) ============
__global__ __launch_bounds__(256) void k_tail(const float* __restrict__ partB, const float* __restrict__ eff_b2,
                                              const float* __restrict__ v_w,
                                              float* __restrict__ out_ep, float* __restrict__ wu)
{
    const int t = threadIdx.x;
    if (blockIdx.x < 6) {
#pragma unroll
        for (int ii = 0; ii < 32; ++ii) {
            int idx = blockIdx.x * TPB + t + ii * 1536;    // 64*768 = 6*256*32
            int r = idx / 768, c = idx - r * 768;
            float v = eff_b2[c];
#pragma unroll
            for (int q = 0; q < 8; ++q) v += partB[(size_t)(q * 64 + r) * 1792 + c];
            out_ep[r * 768 + c] = v;
        }
    } else {
        __shared__ float us[64 * 132];
        int m = blockIdx.x - 6;                 // 0..95
        int h = m / 12, ctile = m % 12;
        for (int n = t; n < 8192; n += TPB) {
            int b = n >> 7, d = n & 127;
            float v = 0.f;
#pragma unroll
            for (int q = 0; q < 8; ++q) v += partB[(size_t)(q * 64 + b) * 1792 + 768 + h * 128 + d];
            us[b * 132 + d] = v;                // u[b, h*128+d]
        }
        __syncthreads();
        int c = ctile * 64 + (t >> 2);
        int bo = t & 3;
        const float* vr = v_w + (size_t)c * 1024 + h * 128;
        float acc[16];
#pragma unroll
        for (int i = 0; i < 16; ++i) acc[i] = 0.f;
        for (int d = 0; d < 128; d += 4) {
            float4 w4 = *(const float4*)(vr + d);
#pragma unroll
            for (int i = 0; i < 16; ++i) {
                const float* ub = &us[(4 * i + bo) * 132 + d];
                acc[i] += w4.x * ub[0] + w4.y * ub[1] + w4.z * ub[2] + w4.w * ub[3];
            }
        }
#pragma unroll
        for (int i = 0; i < 16; ++i) {
            int b = 4 * i + bo;
            wu[(b * 8 + h) * 768 + c] = acc[i];
        }
    }
}

// ============ fused bias + broadcast (512 threads: 8 waves, 2 blocks/CU) ============
__global__ __launch_bounds__(512) void k_biasbc(const float* __restrict__ tok_cause, const float* __restrict__ wu,
                         const float* __restrict__ ls_ptr, float* __restrict__ out_lb)
{
    int b = blockIdx.x, kt = blockIdx.y;
    __shared__ float wuh[8 * 768];     // 24 KB
    __shared__ float bsm[8 * 32];      // bias values [h][k_local]
    for (int n = threadIdx.x; n < 6144; n += 512)
        wuh[n] = wu[b * 6144 + n];
    __syncthreads();
    const int lane = threadIdx.x & 63, w = threadIdx.x >> 6;   // 8 waves
    vf4 wur[3][8];
#pragma unroll
    for (int j = 0; j < 3; ++j)
#pragma unroll
        for (int h = 0; h < 8; ++h)
            wur[j][h] = *(const vf4*)&wuh[h * 768 + (lane + 64 * j) * 4];
    float scale = expf(ls_ptr[0]) * 0.08838834764831845f;
#pragma unroll
    for (int rr = 0; rr < 4; ++rr) {
        int rl = w * 4 + rr;                    // 0..31 local k-row
        int row = kt * 32 + rl;
        const vf4* tr = (const vf4*)(tok_cause + ((size_t)b * 256 + row) * 768);
        vf4 t0 = __builtin_nontemporal_load(tr + lane);
        vf4 t1 = __builtin_nontemporal_load(tr + lane + 64);
        vf4 t2 = __builtin_nontemporal_load(tr + lane + 128);
        float acc[8];
#pragma unroll
        for (int h = 0; h < 8; ++h) {
            acc[h] = t0.x * wur[0][h].x + t0.y * wur[0][h].y + t0.z * wur[0][h].z + t0.w * wur[0][h].w
                   + t1.x * wur[1][h].x + t1.y * wur[1][h].y + t1.z * wur[1][h].z + t1.w * wur[1][h].w
                   + t2.x * wur[2][h].x + t2.y * wur[2][h].y + t2.z * wur[2][h].z + t2.w * wur[2][h].w;
        }
#pragma unroll
        for (int h = 0; h < 8; ++h) {
            float vv = acc[h];
#pragma unroll
            for (int o_ = 32; o_ > 0; o_ >>= 1) vv += __shfl_xor(vv, o_);
            if (lane == 0) bsm[h * 32 + rl] = vv * scale;
        }
    }
    __syncthreads();
    const vf4* bs4 = (const vf4*)bsm;          // [8][8]
    vf4* o4 = (vf4*)out_lb;
    int v = threadIdx.x & 7, sq0 = threadIdx.x >> 3;   // 64 segments per pass
#pragma unroll
    for (int it = 0; it < 32; ++it) {
        int seg = sq0 + it * 64;               // 0..2047 = h*256 + q
        int h = seg >> 8, q = seg & 255;
        vf4 val = bs4[h * 8 + v];
        __builtin_nontemporal_store(val, &o4[(((size_t)(b * 8 + h) * 256 + q) << 6) + kt * 8 + v]);
    }
}

extern "C" void kernel_launch(void* const* d_in, const int* in_sizes, int n_in,
                              void* d_out, int out_size, void* d_ws, size_t ws_size,
                              hipStream_t stream)
{
    (void)in_sizes; (void)n_in; (void)out_size; (void)ws_size;
    const float* emb_cause  = (const float*)d_in[0];
    const float* emb_action = (const float*)d_in[1];
    const float* tok_cause  = (const float*)d_in[2];
    const float* tok_effect = (const float*)d_in[3];
    const float* fuse_ln_g  = (const float*)d_in[4];
    const float* fuse_ln_b  = (const float*)d_in[5];
    const float* fuse_w1    = (const float*)d_in[6];
    const float* fuse_b1    = (const float*)d_in[7];
    const float* fuse_w2    = (const float*)d_in[8];
    const float* fuse_b2    = (const float*)d_in[9];
    const float* delta_ln_g = (const float*)d_in[10];
    const float* delta_ln_b = (const float*)d_in[11];
    const float* delta_w    = (const float*)d_in[12];
    const float* delta_b    = (const float*)d_in[13];
    const float* qg_w       = (const float*)d_in[14];
    const float* qg_b       = (const float*)d_in[15];
    const float* kg_w       = (const float*)d_in[16];
    const float* kg_b       = (const float*)d_in[17];
    const float* eff_ln_g   = (const float*)d_in[18];
    const float* eff_ln_b   = (const float*)d_in[19];
    const float* eff_w1     = (const float*)d_in[20];
    const float* eff_b1     = (const float*)d_in[21];
    const float* eff_w2     = (const float*)d_in[22];
    const float* eff_b2     = (const float*)d_in[23];
    const float* u_w        = (const float*)d_in[24];
    const float* v_w        = (const float*)d_in[25];
    const float* logit_sc   = (const float*)d_in[26];

    float* ws = (float*)d_ws;
    float* ctx    = ws + 0;        // 49152
    float* pp     = ws + 49152;    // 196608
    float* wu     = ws + 245760;   // 393216
    float* stats1 = ws + 638976;   // 128
    float* stats2 = ws + 639104;   // 128  (end 639232 floats = 2.6 MB)

    float* out    = (float*)d_out;
    float* out_qg = out + 0;
    float* out_kg = out + 65536;
    float* out_es = out + 131072;
    float* out_de = out + 180224;
    float* out_lb = out + 229376;
    float* out_ep = out + 33783808;

    // split-K partial buffers in the tail of logit_bias (overwritten last by k_biasbc)
    float* pbase = out_lb + 20000000;
    float* part1 = pbase;             // 12*64*768 = 589824
    float* part2 = pbase + 589824;    // 12*64*768 = 589824
    float* partA = pbase + 1179648;   //  8*64*3584 = 1835008
    float* partB = pbase + 3014656;   //  8*64*1792 = 917504 (end 3.93M < 13.3M spare)

    // 1) cat-LN stats only
    k_stats<<<64, TPB, 0, stream>>>(emb_cause, emb_action, stats1);
    // 2) fuse1 partials (lazy LN) || pool qz 0-1
    {
        G1Args A; A.ec = emb_cause; A.ea = emb_action; A.stats1 = stats1;
        A.flg = fuse_ln_g; A.flb = fuse_ln_b; A.w1 = fuse_w1;
        A.tok_effect = tok_effect; A.part1 = part1; A.pp = pp;
        k_g1<<<528, TPB, 0, stream>>>(A);
    }
    // 3) fuse2 partials (lazy GELU-epilogue of fuse1) || pool qz 2-3
    {
        G2Args A; A.part1 = part1; A.b1 = fuse_b1; A.w2 = fuse_w2;
        A.tok_effect = tok_effect; A.part2 = part2; A.pp = pp;
        k_g2<<<528, TPB, 0, stream>>>(A);
    }
    // 4) ctx + LN stats
    k_ln<<<64, TPB, 0, stream>>>(part2, fuse_b2, ctx, stats2);
    // 5) batchA partials: delta | eff1 (lazy-LN) | qg | kg (raw ctx)
    {
        GAArgs A; A.ctx = ctx; A.stats2 = stats2;
        A.dg = delta_ln_g; A.db = delta_ln_b; A.eg = eff_ln_g; A.eb = eff_ln_b;
        A.delta_w = delta_w; A.eff_w1 = eff_w1; A.qg_w = qg_w; A.kg_w = kg_w; A.partA = partA;
        k_gA<<<448, TPB, 0, stream>>>(A);
    }
    // 6) batchA outputs || batchB partials (eff2 w/ lazy eh, u_w w/ lazy e_shifted)
    {
        MidArgs M; M.partA = partA; M.pp = pp;
        M.delta_b = delta_b; M.eff_b1 = eff_b1; M.qg_b = qg_b; M.kg_b = kg_b;
        M.eff_w2 = eff_w2; M.u_w = u_w; M.partB = partB;
        M.out_de = out_de; M.out_es = out_es; M.out_qg = out_qg; M.out_kg = out_kg;
        k_mid<<<252, TPB, 0, stream>>>(M);
    }
    // 7) effect_pred epilogue || wu fold (lazy u from partB)
    k_tail<<<102, TPB, 0, stream>>>(partB, eff_b2, v_w, out_ep, wu);
    // 8) fused per-(b,h,k) bias + q-broadcast
    k_biasbc<<<dim3(64, 8), 512, 0, stream>>>(tok_cause, wu, logit_sc, out_lb);
}